// Round 1
// baseline (812.675 us; speedup 1.0000x reference)
//
#include <hip/hip_runtime.h>
#include <math.h>

#define VV 8192
#define DD 768

// ---------------------------------------------------------------------------
// k_normalize: one block per row. L2-normalize row (norm accumulated in fp64,
// division like the reference's t / norm).
// ---------------------------------------------------------------------------
__global__ __launch_bounds__(256) void k_normalize(const float* __restrict__ t,
                                                   float* __restrict__ x) {
    int r = blockIdx.x;
    const float* tr = t + (size_t)r * DD;
    float* xr = x + (size_t)r * DD;
    int tid = threadIdx.x;
    float v0 = tr[tid], v1 = tr[tid + 256], v2 = tr[tid + 512];
    double s = (double)v0 * v0 + (double)v1 * v1 + (double)v2 * v2;
#pragma unroll
    for (int o = 32; o > 0; o >>= 1) s += __shfl_down(s, o, 64);
    __shared__ double wsum[4];
    int lane = tid & 63, w = tid >> 6;
    if (lane == 0) wsum[w] = s;
    __syncthreads();
    double tot = wsum[0] + wsum[1] + wsum[2] + wsum[3];
    float norm = fmaxf((float)sqrt(tot), 1e-12f);
    xr[tid] = v0 / norm;
    xr[tid + 256] = v1 / norm;
    xr[tid + 512] = v2 / norm;
}

// ---------------------------------------------------------------------------
// k_colsum: g[k] = sum over rows of x[r][k], fp64. 64 blocks x 128 rows.
// ---------------------------------------------------------------------------
__global__ __launch_bounds__(256) void k_colsum(const float* __restrict__ x,
                                                double* __restrict__ g) {
    int t = threadIdx.x;
    int r0 = blockIdx.x * 128;
    double s0 = 0.0, s1 = 0.0, s2 = 0.0;
    for (int r = r0; r < r0 + 128; ++r) {
        const float* xr = x + (size_t)r * DD;
        s0 += (double)xr[t];
        s1 += (double)xr[t + 256];
        s2 += (double)xr[t + 512];
    }
    atomicAdd(&g[t], s0);
    atomicAdd(&g[t + 256], s1);
    atomicAdd(&g[t + 512], s2);
}

// ---------------------------------------------------------------------------
// k_mean: per row (one wave each): mnum[r] = x_r . g - x_r . x_r  (fp64),
// dd[r] = x_r . x_r (the S-diagonal, ~1). mean_neg = mnum/8191.
// This sidesteps the pairwise pass for the numerically-deadly mean path.
// ---------------------------------------------------------------------------
__global__ __launch_bounds__(256) void k_mean(const float* __restrict__ x,
                                              const double* __restrict__ g,
                                              double* __restrict__ mnum,
                                              double* __restrict__ dd) {
    int r = blockIdx.x * 4 + (threadIdx.x >> 6);
    int lane = threadIdx.x & 63;
    const float* xr = x + (size_t)r * DD;
    double xg = 0.0, xx = 0.0;
#pragma unroll
    for (int k = lane; k < DD; k += 64) {
        double xv = (double)xr[k];
        xg += xv * g[k];
        xx += xv * xv;
    }
#pragma unroll
    for (int o = 32; o > 0; o >>= 1) {
        xg += __shfl_down(xg, o, 64);
        xx += __shfl_down(xx, o, 64);
    }
    if (lane == 0) {
        mnum[r] = xg - xx;
        dd[r] = xx;
    }
}

// ---------------------------------------------------------------------------
// k_cube: the O(V^2 D) pass. Upper-triangle 64x64 tiles; per tile compute
// s_ij = x_i . x_j (fp32, 4x4 register tile per thread), then accumulate
// s^3 into per-row sums for the row side AND (off-diag blocks) the column
// side (s_ji = s_ij, odd power). Diagonal elements skipped (S_off).
// LDS tiles stored transposed [k][m] with pad 68 -> 16B-aligned float4 rows.
// ---------------------------------------------------------------------------
__global__ __launch_bounds__(256) void k_cube(const float* __restrict__ x,
                                              float* __restrict__ rc) {
    const int bi = blockIdx.y, bj = blockIdx.x;
    if (bj < bi) return;

    __shared__ float As[32][68];
    __shared__ float Bs[32][68];
    __shared__ float red[64][17];

    const int tid = threadIdx.x;
    const int tx = tid & 15, ty = tid >> 4;

    float acc[4][4] = {};

    const int lr = tid >> 3;        // 0..31 (row within half-tile)
    const int lk = (tid & 7) << 2;  // 0,4,...,28 (k offset)
    const float* Ab = x + ((size_t)(bi * 64 + lr)) * DD + lk;
    const float* Bb = x + ((size_t)(bj * 64 + lr)) * DD + lk;

    for (int kk = 0; kk < DD; kk += 32) {
        float4 a0 = *(const float4*)(Ab + kk);
        float4 a1 = *(const float4*)(Ab + kk + 32 * DD);
        float4 b0 = *(const float4*)(Bb + kk);
        float4 b1 = *(const float4*)(Bb + kk + 32 * DD);
        __syncthreads();  // previous iteration's reads complete
        As[lk + 0][lr] = a0.x; As[lk + 1][lr] = a0.y;
        As[lk + 2][lr] = a0.z; As[lk + 3][lr] = a0.w;
        As[lk + 0][lr + 32] = a1.x; As[lk + 1][lr + 32] = a1.y;
        As[lk + 2][lr + 32] = a1.z; As[lk + 3][lr + 32] = a1.w;
        Bs[lk + 0][lr] = b0.x; Bs[lk + 1][lr] = b0.y;
        Bs[lk + 2][lr] = b0.z; Bs[lk + 3][lr] = b0.w;
        Bs[lk + 0][lr + 32] = b1.x; Bs[lk + 1][lr + 32] = b1.y;
        Bs[lk + 2][lr + 32] = b1.z; Bs[lk + 3][lr + 32] = b1.w;
        __syncthreads();
#pragma unroll
        for (int k = 0; k < 32; ++k) {
            float av[4], bv[4];
            *(float4*)av = *(const float4*)(&As[k][ty << 2]);
            *(float4*)bv = *(const float4*)(&Bs[k][tx << 2]);
#pragma unroll
            for (int u = 0; u < 4; ++u)
#pragma unroll
                for (int v = 0; v < 4; ++v)
                    acc[u][v] = fmaf(av[u], bv[v], acc[u][v]);
        }
    }

    // cube + skip diagonal, build per-thread row/col partials
    const int gi0 = bi * 64 + (ty << 2);
    const int gj0 = bj * 64 + (tx << 2);
    float rsum[4] = {}, csum[4] = {};
#pragma unroll
    for (int u = 0; u < 4; ++u) {
#pragma unroll
        for (int v = 0; v < 4; ++v) {
            float s = acc[u][v];
            if (gi0 + u == gj0 + v) continue;  // S_off diag is zero
            float c = s * s * s;
            rsum[u] += c;
            csum[v] += c;
        }
    }

    // row-side reduction: rows ty*4+u, 16 partials (one per tx)
    __syncthreads();
#pragma unroll
    for (int u = 0; u < 4; ++u) red[(ty << 2) + u][tx] = rsum[u];
    __syncthreads();
    if (tid < 64) {
        float s = 0.f;
#pragma unroll
        for (int i = 0; i < 16; ++i) s += red[tid][i];
        atomicAdd(&rc[bi * 64 + tid], s);
    }

    if (bi != bj) {
        // col-side (these are rows bj*64.. of S, by symmetry)
        __syncthreads();
#pragma unroll
        for (int v = 0; v < 4; ++v) red[(tx << 2) + v][ty] = csum[v];
        __syncthreads();
        if (tid < 64) {
            float s = 0.f;
#pragma unroll
            for (int i = 0; i < 16; ++i) s += red[tid][i];
            atomicAdd(&rc[bj * 64 + tid], s);
        }
    }
}

// ---------------------------------------------------------------------------
// k_final: out = collapse + 0.2 * sum_i rc_i / (mnum_i/8191 + 1e-6)
// ---------------------------------------------------------------------------
__global__ __launch_bounds__(256) void k_final(const float* __restrict__ rc,
                                               const double* __restrict__ mnum,
                                               const double* __restrict__ dd,
                                               float* __restrict__ out) {
    int tid = threadIdx.x;
    double acc = 0.0, col = 0.0;
    for (int r = tid; r < VV; r += 256) {
        double m = mnum[r] / 8191.0 + 1e-6;
        acc += (double)rc[r] / m;
        double dm = dd[r] - 1.0;
        col += dm * dm;
    }
    __shared__ double sa[256], sc[256];
    sa[tid] = acc;
    sc[tid] = col;
    __syncthreads();
    for (int o = 128; o > 0; o >>= 1) {
        if (tid < o) {
            sa[tid] += sa[tid + o];
            sc[tid] += sc[tid + o];
        }
        __syncthreads();
    }
    if (tid == 0) out[0] = (float)(sc[0] + 0.2 * sa[0]);
}

// ---------------------------------------------------------------------------
extern "C" void kernel_launch(void* const* d_in, const int* in_sizes, int n_in,
                              void* d_out, int out_size, void* d_ws, size_t ws_size,
                              hipStream_t stream) {
    const float* t = (const float*)d_in[0];
    float* out = (float*)d_out;

    char* ws = (char*)d_ws;
    float* x = (float*)ws;
    size_t off = (size_t)VV * DD * sizeof(float);          // 25,165,824
    double* g = (double*)(ws + off);  off += DD * sizeof(double);
    double* mnum = (double*)(ws + off); off += VV * sizeof(double);
    double* dd = (double*)(ws + off);  off += VV * sizeof(double);
    float* rc = (float*)(ws + off);    off += VV * sizeof(float);

    hipMemsetAsync(g, 0, DD * sizeof(double), stream);
    hipMemsetAsync(rc, 0, VV * sizeof(float), stream);

    k_normalize<<<VV, 256, 0, stream>>>(t, x);
    k_colsum<<<64, 256, 0, stream>>>(x, g);
    k_mean<<<VV / 4, 256, 0, stream>>>(x, g, mnum, dd);
    k_cube<<<dim3(128, 128), 256, 0, stream>>>(x, rc);
    k_final<<<1, 256, 0, stream>>>(rc, mnum, dd, out);
}

// Round 2
// 308.193 us; speedup vs baseline: 2.6369x; 2.6369x over previous
//
#include <hip/hip_runtime.h>
#include <math.h>

#define VV 8192
#define DD 768

typedef __attribute__((ext_vector_type(8))) short bf16x8;
typedef __attribute__((ext_vector_type(4))) float f32x4;

// RNE float -> bf16 bits (normal values; inputs are tame)
__device__ inline ushort f2bf(float f) {
    uint u = __float_as_uint(f);
    uint r = (u + 0x7fffu + ((u >> 16) & 1u)) >> 16;
    return (ushort)r;
}
__device__ inline float bf2f(ushort h) { return __uint_as_float(((uint)h) << 16); }

__device__ inline void gload16(const ushort* g, ushort* l) {
    __builtin_amdgcn_global_load_lds(
        (const __attribute__((address_space(1))) void*)g,
        (__attribute__((address_space(3))) void*)l, 16, 0, 0);
}

// ---------------------------------------------------------------------------
// k_normpack: L2-normalize rows (fp64 norm accum) -> x (fp32), xh/xl (bf16
// hi/lo split for the MFMA cube pass).
// ---------------------------------------------------------------------------
__global__ __launch_bounds__(256) void k_normpack(const float* __restrict__ t,
                                                  float* __restrict__ x,
                                                  ushort* __restrict__ xh,
                                                  ushort* __restrict__ xl) {
    int r = blockIdx.x;
    const float* tr = t + (size_t)r * DD;
    int tid = threadIdx.x;
    float v0 = tr[tid], v1 = tr[tid + 256], v2 = tr[tid + 512];
    double s = (double)v0 * v0 + (double)v1 * v1 + (double)v2 * v2;
#pragma unroll
    for (int o = 32; o > 0; o >>= 1) s += __shfl_down(s, o, 64);
    __shared__ double wsum[4];
    int lane = tid & 63, w = tid >> 6;
    if (lane == 0) wsum[w] = s;
    __syncthreads();
    double tot = wsum[0] + wsum[1] + wsum[2] + wsum[3];
    float norm = fmaxf((float)sqrt(tot), 1e-12f);
    size_t base = (size_t)r * DD;
#pragma unroll
    for (int q = 0; q < 3; ++q) {
        int k = tid + q * 256;
        float v = (q == 0 ? v0 : (q == 1 ? v1 : v2)) / norm;
        x[base + k] = v;
        ushort h = f2bf(v);
        xh[base + k] = h;
        xl[base + k] = f2bf(v - bf2f(h));
    }
}

// ---------------------------------------------------------------------------
// k_colsum: g[k] = sum over rows of x[r][k], fp64.
// ---------------------------------------------------------------------------
__global__ __launch_bounds__(256) void k_colsum(const float* __restrict__ x,
                                                double* __restrict__ g) {
    int t = threadIdx.x;
    int r0 = blockIdx.x * 128;
    double s0 = 0.0, s1 = 0.0, s2 = 0.0;
    for (int r = r0; r < r0 + 128; ++r) {
        const float* xr = x + (size_t)r * DD;
        s0 += (double)xr[t];
        s1 += (double)xr[t + 256];
        s2 += (double)xr[t + 512];
    }
    atomicAdd(&g[t], s0);
    atomicAdd(&g[t + 256], s1);
    atomicAdd(&g[t + 512], s2);
}

// ---------------------------------------------------------------------------
// k_mean: mnum[r] = x_r.g - x_r.x_r (fp64); dd[r] = x_r.x_r (S diagonal).
// mean_neg = mnum/8191. Exact mean path -- do not touch (numerically deadly).
// ---------------------------------------------------------------------------
__global__ __launch_bounds__(256) void k_mean(const float* __restrict__ x,
                                              const double* __restrict__ g,
                                              double* __restrict__ mnum,
                                              double* __restrict__ dd) {
    int r = blockIdx.x * 4 + (threadIdx.x >> 6);
    int lane = threadIdx.x & 63;
    const float* xr = x + (size_t)r * DD;
    double xg = 0.0, xx = 0.0;
#pragma unroll
    for (int k = lane; k < DD; k += 64) {
        double xv = (double)xr[k];
        xg += xv * g[k];
        xx += xv * xv;
    }
#pragma unroll
    for (int o = 32; o > 0; o >>= 1) {
        xg += __shfl_down(xg, o, 64);
        xx += __shfl_down(xx, o, 64);
    }
    if (lane == 0) {
        mnum[r] = xg - xx;
        dd[r] = xx;
    }
}

// ---------------------------------------------------------------------------
// k_cube: bf16 MFMA pass. S = X.X^T via 3-term hi/lo split:
//   seg0 hi.hi, seg1 lo.hi, seg2 hi.lo  (lo.lo dropped, ~2^-18 rel)
// 128x128 tiles, upper triangle; 4 waves (2x2), each 64x64 = 4x4 frags of
// 16x16x32 bf16 MFMA. LDS tiles [128][64] bf16, XOR-swizzled (byte ^=
// (row&7)<<4) staged via global_load_lds w=16 with pre-swizzled global src.
// Epilogue cubes, skips diagonal, reduces to per-row sums (row side + col
// side by symmetry; diag blocks row-side only).
// ---------------------------------------------------------------------------
__global__ __launch_bounds__(256) void k_cube(const ushort* __restrict__ xh,
                                              const ushort* __restrict__ xl,
                                              float* __restrict__ rc) {
    const int bi = blockIdx.y, bj = blockIdx.x;
    if (bj < bi) return;

    __shared__ ushort As[128 * 64];
    __shared__ ushort Bs[128 * 64];

    const int tid = threadIdx.x;
    const int lane = tid & 63;
    const int wid = tid >> 6;
    const int wm = wid >> 1, wn = wid & 1;
    const int l15 = lane & 15, li4 = lane >> 4;

    f32x4 acc[4][4];
#pragma unroll
    for (int a = 0; a < 4; ++a)
#pragma unroll
        for (int b = 0; b < 4; ++b) acc[a][b] = (f32x4){0.f, 0.f, 0.f, 0.f};

    // staging descriptors: li = p*256+tid; row=li>>3, slot=li&7 (16B slots)
    size_t offA[4], offB[4];
    int ldso[4];
#pragma unroll
    for (int p = 0; p < 4; ++p) {
        int li = p * 256 + tid;
        int row = li >> 3, slot = li & 7;
        int sl2 = slot ^ (row & 7);  // pre-swizzled source slot
        offA[p] = (size_t)(bi * 128 + row) * DD + sl2 * 8;
        offB[p] = (size_t)(bj * 128 + row) * DD + sl2 * 8;
        ldso[p] = li * 8;  // ushort units, linear (lane-order) dest
    }

#pragma unroll
    for (int seg = 0; seg < 3; ++seg) {
        const ushort* A = (seg == 1) ? xl : xh;
        const ushort* B = (seg == 2) ? xl : xh;
        for (int kk = 0; kk < 12; ++kk) {
            int k0 = kk * 64;
#pragma unroll
            for (int p = 0; p < 4; ++p) {
                gload16(A + offA[p] + k0, &As[ldso[p]]);
                gload16(B + offB[p] + k0, &Bs[ldso[p]]);
            }
            __syncthreads();  // drains vmcnt, data visible
#pragma unroll
            for (int h = 0; h < 2; ++h) {
                bf16x8 av[4], bv[4];
#pragma unroll
                for (int f = 0; f < 4; ++f) {
                    int rowA = wm * 64 + f * 16 + l15;
                    int slot = h * 4 + li4;
                    av[f] = *(const bf16x8*)(As + rowA * 64 +
                                             ((slot ^ (rowA & 7)) << 3));
                    int rowB = wn * 64 + f * 16 + l15;
                    bv[f] = *(const bf16x8*)(Bs + rowB * 64 +
                                             ((slot ^ (rowB & 7)) << 3));
                }
#pragma unroll
                for (int fm = 0; fm < 4; ++fm)
#pragma unroll
                    for (int fn = 0; fn < 4; ++fn)
                        acc[fm][fn] = __builtin_amdgcn_mfma_f32_16x16x32_bf16(
                            av[fm], bv[fn], acc[fm][fn], 0, 0, 0);
            }
            __syncthreads();  // readers done before next stage overwrites
        }
    }

    // epilogue: cube, skip diag, per-row reductions
    const bool dblk = (bi == bj);
    float rsum[4][4];  // [fm][reg]
    float csum[4];     // [fn]
#pragma unroll
    for (int a = 0; a < 4; ++a) {
        csum[a] = 0.f;
#pragma unroll
        for (int b = 0; b < 4; ++b) rsum[a][b] = 0.f;
    }
#pragma unroll
    for (int fm = 0; fm < 4; ++fm)
#pragma unroll
        for (int fn = 0; fn < 4; ++fn)
#pragma unroll
            for (int r = 0; r < 4; ++r) {
                float s = acc[fm][fn][r];
                float c = s * s * s;
                if (dblk && wm == wn && fm == fn && (li4 * 4 + r) == l15)
                    c = 0.f;  // S_off diagonal
                rsum[fm][r] += c;
                csum[fn] += c;
            }

    // row side: reduce across the 16 col-lanes
#pragma unroll
    for (int o = 1; o < 16; o <<= 1)
#pragma unroll
        for (int fm = 0; fm < 4; ++fm)
#pragma unroll
            for (int r = 0; r < 4; ++r)
                rsum[fm][r] += __shfl_xor(rsum[fm][r], o, 64);
    if (l15 == 0) {
#pragma unroll
        for (int fm = 0; fm < 4; ++fm)
#pragma unroll
            for (int r = 0; r < 4; ++r)
                atomicAdd(&rc[bi * 128 + wm * 64 + fm * 16 + li4 * 4 + r],
                          rsum[fm][r]);
    }

    // col side (rows bj*... of S by symmetry; off-diag blocks only)
    if (!dblk) {
#pragma unroll
        for (int o = 16; o < 64; o <<= 1)
#pragma unroll
            for (int fn = 0; fn < 4; ++fn) csum[fn] += __shfl_xor(csum[fn], o, 64);
        if (li4 == 0) {
#pragma unroll
            for (int fn = 0; fn < 4; ++fn)
                atomicAdd(&rc[bj * 128 + wn * 64 + fn * 16 + l15], csum[fn]);
        }
    }
}

// ---------------------------------------------------------------------------
// k_final: out = collapse + 0.2 * sum_i rc_i / (mnum_i/8191 + 1e-6)
// ---------------------------------------------------------------------------
__global__ __launch_bounds__(256) void k_final(const float* __restrict__ rc,
                                               const double* __restrict__ mnum,
                                               const double* __restrict__ dd,
                                               float* __restrict__ out) {
    int tid = threadIdx.x;
    double acc = 0.0, col = 0.0;
    for (int r = tid; r < VV; r += 256) {
        double m = mnum[r] / 8191.0 + 1e-6;
        acc += (double)rc[r] / m;
        double dm = dd[r] - 1.0;
        col += dm * dm;
    }
    __shared__ double sa[256], sc[256];
    sa[tid] = acc;
    sc[tid] = col;
    __syncthreads();
    for (int o = 128; o > 0; o >>= 1) {
        if (tid < o) {
            sa[tid] += sa[tid + o];
            sc[tid] += sc[tid + o];
        }
        __syncthreads();
    }
    if (tid == 0) out[0] = (float)(sc[0] + 0.2 * sa[0]);
}

// ---------------------------------------------------------------------------
extern "C" void kernel_launch(void* const* d_in, const int* in_sizes, int n_in,
                              void* d_out, int out_size, void* d_ws, size_t ws_size,
                              hipStream_t stream) {
    const float* t = (const float*)d_in[0];
    float* out = (float*)d_out;

    char* ws = (char*)d_ws;
    float* x = (float*)ws;
    size_t off = (size_t)VV * DD * sizeof(float);           // 25.2 MB
    ushort* xh = (ushort*)(ws + off); off += (size_t)VV * DD * sizeof(ushort);
    ushort* xl = (ushort*)(ws + off); off += (size_t)VV * DD * sizeof(ushort);
    double* g = (double*)(ws + off);  off += DD * sizeof(double);
    double* mnum = (double*)(ws + off); off += VV * sizeof(double);
    double* dd = (double*)(ws + off);  off += VV * sizeof(double);
    float* rc = (float*)(ws + off);    off += VV * sizeof(float);

    hipMemsetAsync(g, 0, DD * sizeof(double), stream);
    hipMemsetAsync(rc, 0, VV * sizeof(float), stream);

    k_normpack<<<VV, 256, 0, stream>>>(t, x, xh, xl);
    k_colsum<<<64, 256, 0, stream>>>(x, g);
    k_mean<<<VV / 4, 256, 0, stream>>>(x, g, mnum, dd);
    k_cube<<<dim3(64, 64), 256, 0, stream>>>(xh, xl, rc);
    k_final<<<1, 256, 0, stream>>>(rc, mnum, dd, out);
}

// Round 3
// 289.927 us; speedup vs baseline: 2.8030x; 1.0630x over previous
//
#include <hip/hip_runtime.h>
#include <math.h>

#define VV 8192
#define DD 768

typedef __attribute__((ext_vector_type(8))) short bf16x8;
typedef __attribute__((ext_vector_type(4))) float f32x4;

// RNE float -> bf16 bits
__device__ inline ushort f2bf(float f) {
    uint u = __float_as_uint(f);
    uint r = (u + 0x7fffu + ((u >> 16) & 1u)) >> 16;
    return (ushort)r;
}
__device__ inline float bf2f(ushort h) { return __uint_as_float(((uint)h) << 16); }

__device__ inline void gload16(const ushort* g, ushort* l) {
    __builtin_amdgcn_global_load_lds(
        (const __attribute__((address_space(1))) void*)g,
        (__attribute__((address_space(3))) void*)l, 16, 0, 0);
}

// ---------------------------------------------------------------------------
// k_normpack: L2-normalize rows (fp64 norm accum) -> x (fp32), xh/xl (bf16
// hi/lo split for the MFMA cube pass).
// ---------------------------------------------------------------------------
__global__ __launch_bounds__(256) void k_normpack(const float* __restrict__ t,
                                                  float* __restrict__ x,
                                                  ushort* __restrict__ xh,
                                                  ushort* __restrict__ xl) {
    int r = blockIdx.x;
    const float* tr = t + (size_t)r * DD;
    int tid = threadIdx.x;
    float v0 = tr[tid], v1 = tr[tid + 256], v2 = tr[tid + 512];
    double s = (double)v0 * v0 + (double)v1 * v1 + (double)v2 * v2;
#pragma unroll
    for (int o = 32; o > 0; o >>= 1) s += __shfl_down(s, o, 64);
    __shared__ double wsum[4];
    int lane = tid & 63, w = tid >> 6;
    if (lane == 0) wsum[w] = s;
    __syncthreads();
    double tot = wsum[0] + wsum[1] + wsum[2] + wsum[3];
    float norm = fmaxf((float)sqrt(tot), 1e-12f);
    size_t base = (size_t)r * DD;
#pragma unroll
    for (int q = 0; q < 3; ++q) {
        int k = tid + q * 256;
        float v = (q == 0 ? v0 : (q == 1 ? v1 : v2)) / norm;
        x[base + k] = v;
        ushort h = f2bf(v);
        xh[base + k] = h;
        xl[base + k] = f2bf(v - bf2f(h));
    }
}

// ---------------------------------------------------------------------------
// k_colsum: g[k] = sum over rows of x[r][k], fp64.
// ---------------------------------------------------------------------------
__global__ __launch_bounds__(256) void k_colsum(const float* __restrict__ x,
                                                double* __restrict__ g) {
    int t = threadIdx.x;
    int r0 = blockIdx.x * 128;
    double s0 = 0.0, s1 = 0.0, s2 = 0.0;
    for (int r = r0; r < r0 + 128; ++r) {
        const float* xr = x + (size_t)r * DD;
        s0 += (double)xr[t];
        s1 += (double)xr[t + 256];
        s2 += (double)xr[t + 512];
    }
    atomicAdd(&g[t], s0);
    atomicAdd(&g[t + 256], s1);
    atomicAdd(&g[t + 512], s2);
}

// ---------------------------------------------------------------------------
// k_mean: mnum[r] = x_r.g - x_r.x_r (fp64); dd[r] = x_r.x_r (S diagonal).
// Exact mean path -- numerically deadly, do not approximate.
// ---------------------------------------------------------------------------
__global__ __launch_bounds__(256) void k_mean(const float* __restrict__ x,
                                              const double* __restrict__ g,
                                              double* __restrict__ mnum,
                                              double* __restrict__ dd) {
    int r = blockIdx.x * 4 + (threadIdx.x >> 6);
    int lane = threadIdx.x & 63;
    const float* xr = x + (size_t)r * DD;
    double xg = 0.0, xx = 0.0;
#pragma unroll
    for (int k = lane; k < DD; k += 64) {
        double xv = (double)xr[k];
        xg += xv * g[k];
        xx += xv * xv;
    }
#pragma unroll
    for (int o = 32; o > 0; o >>= 1) {
        xg += __shfl_down(xg, o, 64);
        xx += __shfl_down(xx, o, 64);
    }
    if (lane == 0) {
        mnum[r] = xg - xx;
        dd[r] = xx;
    }
}

// ---------------------------------------------------------------------------
// k_cube: 256x256-tile bf16 MFMA pass, prefetch-pipelined (counted vmcnt +
// raw barriers). S = X.X^T via 3-term hi/lo split (hi.hi + lo.hi + hi.lo).
// 8 waves (2M x 4N), per-wave 128x64 = 8x4 frags of 16x16x32 bf16.
// LDS: A,B double-buffered [2][256][64] bf16 (128 KiB), XOR slot-swizzle
// (slot ^= row&7) staged via global_load_lds w=16 with pre-swizzled source.
// Triangular grid (528 blocks) + bijective XCD swizzle.
// Epilogue cubes, skips diagonal, per-row sums (row side + col side).
// ---------------------------------------------------------------------------
__global__ __launch_bounds__(512, 2) void k_cube(const ushort* __restrict__ xh,
                                                 const ushort* __restrict__ xl,
                                                 float* __restrict__ rc) {
    // triangular decode + XCD-bijective swizzle (528 = 8*66)
    int wg = ((int)blockIdx.x & 7) * 66 + ((int)blockIdx.x >> 3);
    int bi = 0, rem = wg;
    while (rem >= 32 - bi) { rem -= 32 - bi; ++bi; }
    int bj = bi + rem;

    __shared__ __align__(16) ushort As[2][256 * 64];
    __shared__ __align__(16) ushort Bs[2][256 * 64];

    const int tid = threadIdx.x;
    const int lane = tid & 63;
    const int wid = tid >> 6;           // 0..7
    const int wm = wid >> 2, wn = wid & 3;
    const int l15 = lane & 15, li4 = lane >> 4;

    f32x4 acc[8][4];
#pragma unroll
    for (int f = 0; f < 8; ++f)
#pragma unroll
        for (int n = 0; n < 4; ++n) acc[f][n] = (f32x4){0.f, 0.f, 0.f, 0.f};

    // staging descriptors: li = p*512+tid; row=li>>3 (0..255), slot=li&7
    int aoff[4], boff[4], ldso[4];
#pragma unroll
    for (int p = 0; p < 4; ++p) {
        int li = p * 512 + tid;
        int row = li >> 3, slot = li & 7;
        int sl2 = slot ^ (row & 7);  // pre-swizzled source slot
        aoff[p] = (bi * 256 + row) * DD + sl2 * 8;
        boff[p] = (bj * 256 + row) * DD + sl2 * 8;
        ldso[p] = li * 8;  // linear LDS dest (ushort units)
    }

    // prologue: stage K-step 0 (seg 0: hi.hi, k0=0) into buf 0
#pragma unroll
    for (int p = 0; p < 4; ++p) {
        gload16(xh + aoff[p], &As[0][ldso[p]]);
        gload16(xh + boff[p], &Bs[0][ldso[p]]);
    }

    int cur = 0;
    for (int t = 0; t < 36; ++t) {
        if (t < 35) {
            // issue next K-step's stage into the other buffer
            int tt = t + 1;
            int seg = (tt >= 24) ? 2 : ((tt >= 12) ? 1 : 0);
            int k0 = (tt - seg * 12) << 6;
            const ushort* A = (seg == 1) ? xl : xh;
            const ushort* B = (seg == 2) ? xl : xh;
            int nb = cur ^ 1;
#pragma unroll
            for (int p = 0; p < 4; ++p) {
                gload16(A + aoff[p] + k0, &As[nb][ldso[p]]);
                gload16(B + boff[p] + k0, &Bs[nb][ldso[p]]);
            }
            // wait only for current step's 8 loads (next 8 stay in flight)
            asm volatile("s_waitcnt vmcnt(8)" ::: "memory");
        } else {
            asm volatile("s_waitcnt vmcnt(0)" ::: "memory");
        }
        __builtin_amdgcn_sched_barrier(0);
        asm volatile("s_barrier" ::: "memory");  // buf[cur] visible to all

        const ushort* Ab = &As[cur][0];
        const ushort* Bb = &Bs[cur][0];
#pragma unroll
        for (int h = 0; h < 2; ++h) {
            bf16x8 av[8], bv[4];
            const int swz = (((h << 2) + li4) ^ (l15 & 7)) << 3;
#pragma unroll
            for (int f = 0; f < 8; ++f)
                av[f] = *(const bf16x8*)(Ab + (wm * 128 + f * 16 + l15) * 64 + swz);
#pragma unroll
            for (int n = 0; n < 4; ++n)
                bv[n] = *(const bf16x8*)(Bb + (wn * 64 + n * 16 + l15) * 64 + swz);
            __builtin_amdgcn_s_setprio(1);
#pragma unroll
            for (int f = 0; f < 8; ++f)
#pragma unroll
                for (int n = 0; n < 4; ++n)
                    acc[f][n] = __builtin_amdgcn_mfma_f32_16x16x32_bf16(
                        av[f], bv[n], acc[f][n], 0, 0, 0);
            __builtin_amdgcn_s_setprio(0);
        }
        __builtin_amdgcn_sched_barrier(0);
        asm volatile("s_barrier" ::: "memory");  // reads done before overwrite
        cur ^= 1;
    }

    // epilogue: cube, skip diag, per-row reductions
    const bool dblk = (bi == bj);
    float rsum[8][4];  // [f][reg]
    float csum[4];     // [n]
#pragma unroll
    for (int n = 0; n < 4; ++n) csum[n] = 0.f;
#pragma unroll
    for (int f = 0; f < 8; ++f)
#pragma unroll
        for (int r = 0; r < 4; ++r) rsum[f][r] = 0.f;

#pragma unroll
    for (int f = 0; f < 8; ++f)
#pragma unroll
        for (int n = 0; n < 4; ++n)
#pragma unroll
            for (int r = 0; r < 4; ++r) {
                float s = acc[f][n][r];
                float c = s * s * s;
                int ri = wm * 128 + f * 16 + li4 * 4 + r;   // row in tile
                int cj = wn * 64 + n * 16 + l15;            // col in tile
                if (dblk && ri == cj) c = 0.f;              // S_off diagonal
                rsum[f][r] += c;
                csum[n] += c;
            }

    // row side: reduce across the 16 col-lanes (l15)
#pragma unroll
    for (int o = 1; o < 16; o <<= 1)
#pragma unroll
        for (int f = 0; f < 8; ++f)
#pragma unroll
            for (int r = 0; r < 4; ++r)
                rsum[f][r] += __shfl_xor(rsum[f][r], o, 64);
    if (l15 == 0) {
#pragma unroll
        for (int f = 0; f < 8; ++f)
#pragma unroll
            for (int r = 0; r < 4; ++r)
                atomicAdd(&rc[bi * 256 + wm * 128 + f * 16 + li4 * 4 + r],
                          rsum[f][r]);
    }

    // col side (rows bj*.. of S by symmetry; off-diag blocks only)
    if (!dblk) {
#pragma unroll
        for (int o = 16; o < 64; o <<= 1)
#pragma unroll
            for (int n = 0; n < 4; ++n) csum[n] += __shfl_xor(csum[n], o, 64);
        if (li4 == 0) {
#pragma unroll
            for (int n = 0; n < 4; ++n)
                atomicAdd(&rc[bj * 256 + wn * 64 + n * 16 + l15], csum[n]);
        }
    }
}

// ---------------------------------------------------------------------------
// k_final: out = collapse + 0.2 * sum_i rc_i / (mnum_i/8191 + 1e-6)
// ---------------------------------------------------------------------------
__global__ __launch_bounds__(256) void k_final(const float* __restrict__ rc,
                                               const double* __restrict__ mnum,
                                               const double* __restrict__ dd,
                                               float* __restrict__ out) {
    int tid = threadIdx.x;
    double acc = 0.0, col = 0.0;
    for (int r = tid; r < VV; r += 256) {
        double m = mnum[r] / 8191.0 + 1e-6;
        acc += (double)rc[r] / m;
        double dm = dd[r] - 1.0;
        col += dm * dm;
    }
    __shared__ double sa[256], sc[256];
    sa[tid] = acc;
    sc[tid] = col;
    __syncthreads();
    for (int o = 128; o > 0; o >>= 1) {
        if (tid < o) {
            sa[tid] += sa[tid + o];
            sc[tid] += sc[tid + o];
        }
        __syncthreads();
    }
    if (tid == 0) out[0] = (float)(sc[0] + 0.2 * sa[0]);
}

// ---------------------------------------------------------------------------
extern "C" void kernel_launch(void* const* d_in, const int* in_sizes, int n_in,
                              void* d_out, int out_size, void* d_ws, size_t ws_size,
                              hipStream_t stream) {
    const float* t = (const float*)d_in[0];
    float* out = (float*)d_out;

    char* ws = (char*)d_ws;
    float* x = (float*)ws;
    size_t off = (size_t)VV * DD * sizeof(float);           // 25.2 MB
    ushort* xh = (ushort*)(ws + off); off += (size_t)VV * DD * sizeof(ushort);
    ushort* xl = (ushort*)(ws + off); off += (size_t)VV * DD * sizeof(ushort);
    double* g = (double*)(ws + off);  off += DD * sizeof(double);
    double* mnum = (double*)(ws + off); off += VV * sizeof(double);
    double* dd = (double*)(ws + off);  off += VV * sizeof(double);
    float* rc = (float*)(ws + off);    off += VV * sizeof(float);

    hipMemsetAsync(g, 0, DD * sizeof(double), stream);
    hipMemsetAsync(rc, 0, VV * sizeof(float), stream);

    k_normpack<<<VV, 256, 0, stream>>>(t, x, xh, xl);
    k_colsum<<<64, 256, 0, stream>>>(x, g);
    k_mean<<<VV / 4, 256, 0, stream>>>(x, g, mnum, dd);
    k_cube<<<528, 512, 0, stream>>>(xh, xl, rc);
    k_final<<<1, 256, 0, stream>>>(rc, mnum, dd, out);
}

// Round 4
// 240.251 us; speedup vs baseline: 3.3826x; 1.2068x over previous
//
#include <hip/hip_runtime.h>
#include <math.h>

#define VV 8192
#define DD 768

typedef __attribute__((ext_vector_type(8))) short bf16x8;
typedef __attribute__((ext_vector_type(4))) float f32x4;

// RNE float -> bf16 bits
__device__ inline ushort f2bf(float f) {
    uint u = __float_as_uint(f);
    uint r = (u + 0x7fffu + ((u >> 16) & 1u)) >> 16;
    return (ushort)r;
}
__device__ inline float bf2f(ushort h) { return __uint_as_float(((uint)h) << 16); }

__device__ inline void gload16(const ushort* g, ushort* l) {
    __builtin_amdgcn_global_load_lds(
        (const __attribute__((address_space(1))) void*)g,
        (__attribute__((address_space(3))) void*)l, 16, 0, 0);
}
#define BAR() asm volatile("s_barrier" ::: "memory")
#define SCHED0() __builtin_amdgcn_sched_barrier(0)

// ---------------------------------------------------------------------------
// k_normpack: L2-normalize rows (fp64 norm accum) -> x (fp32), xh/xl (bf16
// hi/lo split for the MFMA cube pass).
// ---------------------------------------------------------------------------
__global__ __launch_bounds__(256) void k_normpack(const float* __restrict__ t,
                                                  float* __restrict__ x,
                                                  ushort* __restrict__ xh,
                                                  ushort* __restrict__ xl) {
    int r = blockIdx.x;
    const float* tr = t + (size_t)r * DD;
    int tid = threadIdx.x;
    float v0 = tr[tid], v1 = tr[tid + 256], v2 = tr[tid + 512];
    double s = (double)v0 * v0 + (double)v1 * v1 + (double)v2 * v2;
#pragma unroll
    for (int o = 32; o > 0; o >>= 1) s += __shfl_down(s, o, 64);
    __shared__ double wsum[4];
    int lane = tid & 63, w = tid >> 6;
    if (lane == 0) wsum[w] = s;
    __syncthreads();
    double tot = wsum[0] + wsum[1] + wsum[2] + wsum[3];
    float norm = fmaxf((float)sqrt(tot), 1e-12f);
    size_t base = (size_t)r * DD;
#pragma unroll
    for (int q = 0; q < 3; ++q) {
        int k = tid + q * 256;
        float v = (q == 0 ? v0 : (q == 1 ? v1 : v2)) / norm;
        x[base + k] = v;
        ushort h = f2bf(v);
        xh[base + k] = h;
        xl[base + k] = f2bf(v - bf2f(h));
    }
}

// ---------------------------------------------------------------------------
// k_colsum: g[k] = sum over rows of x[r][k], fp64. 256 blocks x 32 rows.
// ---------------------------------------------------------------------------
__global__ __launch_bounds__(256) void k_colsum(const float* __restrict__ x,
                                                double* __restrict__ g) {
    int t = threadIdx.x;
    int r0 = blockIdx.x * 32;
    double s0 = 0.0, s1 = 0.0, s2 = 0.0;
    for (int r = r0; r < r0 + 32; ++r) {
        const float* xr = x + (size_t)r * DD;
        s0 += (double)xr[t];
        s1 += (double)xr[t + 256];
        s2 += (double)xr[t + 512];
    }
    atomicAdd(&g[t], s0);
    atomicAdd(&g[t + 256], s1);
    atomicAdd(&g[t + 512], s2);
}

// ---------------------------------------------------------------------------
// k_mean: mnum[r] = x_r.g - x_r.x_r (fp64); dd[r] = x_r.x_r (S diagonal).
// Exact mean path -- numerically deadly, do not approximate.
// ---------------------------------------------------------------------------
__global__ __launch_bounds__(256) void k_mean(const float* __restrict__ x,
                                              const double* __restrict__ g,
                                              double* __restrict__ mnum,
                                              double* __restrict__ dd) {
    int r = blockIdx.x * 4 + (threadIdx.x >> 6);
    int lane = threadIdx.x & 63;
    const float* xr = x + (size_t)r * DD;
    double xg = 0.0, xx = 0.0;
#pragma unroll
    for (int k = lane; k < DD; k += 64) {
        double xv = (double)xr[k];
        xg += xv * g[k];
        xx += xv * xv;
    }
#pragma unroll
    for (int o = 32; o > 0; o >>= 1) {
        xg += __shfl_down(xg, o, 64);
        xx += __shfl_down(xx, o, 64);
    }
    if (lane == 0) {
        mnum[r] = xg - xx;
        dd[r] = xx;
    }
}

// ---------------------------------------------------------------------------
// k_cube: bf16 MFMA pass, m201-style 4-phase-per-K-tile schedule.
// S = X.X^T via 3-term hi/lo split (hi.hi + lo.hi + hi.lo).
// Grid 576: bids 0..511 = first 512 triangle tiles (256^2, 8 waves 2Mx4N,
// per-wave 128x64), XCD-swizzled; bids 512..575 = the last 16 tiles split
// into 4 quarter-tiles (128^2) each, dispatched last to kill the
// 528-vs-256CU quantization tail.
// LDS per K-tile buf: A/B split into k-half arrays [256][32] bf16 -- row
// stride 64B makes frag reads naturally bank-conflict-free AND staging
// destinations contiguous (no swizzle needed). Double-buffered = 128 KiB.
// Counted vmcnt(4) twice per K-tile (never 0 mid-loop); 2 barriers +
// setprio per phase.
// ---------------------------------------------------------------------------
__global__ __launch_bounds__(512, 2) void k_cube(const ushort* __restrict__ xh,
                                                 const ushort* __restrict__ xl,
                                                 float* __restrict__ rc) {
    __shared__ ushort LDS[65536];  // 128 KiB

    const int bid = blockIdx.x;
    bool quarter;
    int wg, q;
    if (bid < 512) {  // big tiles, XCD-bijective swizzle (512 = 8*64)
        quarter = false;
        wg = (bid & 7) * 64 + (bid >> 3);
        q = 0;
    } else {  // quarter tiles of parents 512..527, dispatched last
        quarter = true;
        wg = 512 + ((bid - 512) >> 2);
        q = (bid - 512) & 3;
    }
    int bi = 0, rem = wg;
    while (rem >= 32 - bi) { rem -= 32 - bi; ++bi; }
    const int bj = bi + rem;

    const int tid = threadIdx.x;
    const int lane = tid & 63;
    const int wid = tid >> 6;
    const int l15 = lane & 15, li4 = lane >> 4;

    if (!quarter) {
        const int wm = wid >> 2, wn = wid & 3;  // 2M x 4N, per-wave 128x64
        const int aoff = (wm * 128 + l15) * 32 + li4 * 8;
        const int boff = (wn * 64 + l15) * 32 + li4 * 8;
        const int li0 = tid, li1 = tid + 512;
        const int gA0 = (bi * 256 + (li0 >> 2)) * DD + (li0 & 3) * 8;
        const int gA1 = (bi * 256 + (li1 >> 2)) * DD + (li1 & 3) * 8;
        const int gB0 = (bj * 256 + (li0 >> 2)) * DD + (li0 & 3) * 8;
        const int gB1 = (bj * 256 + (li1 >> 2)) * DD + (li1 & 3) * 8;
        const int ld0 = li0 * 8, ld1 = li1 * 8;

        f32x4 acc[8][4];
#pragma unroll
        for (int f = 0; f < 8; ++f)
#pragma unroll
            for (int n = 0; n < 4; ++n) acc[f][n] = (f32x4){0.f, 0.f, 0.f, 0.f};

        // prologue: stage tile 0 (seg0: A=B=xh), order Ak0,Bk0,Ak1,Bk1
        gload16(xh + gA0, LDS + ld0);             gload16(xh + gA1, LDS + ld1);
        gload16(xh + gB0, LDS + 16384 + ld0);     gload16(xh + gB1, LDS + 16384 + ld1);
        gload16(xh + gA0 + 32, LDS + 8192 + ld0); gload16(xh + gA1 + 32, LDS + 8192 + ld1);
        gload16(xh + gB0 + 32, LDS + 24576 + ld0);gload16(xh + gB1 + 32, LDS + 24576 + ld1);
        asm volatile("s_waitcnt vmcnt(4)" ::: "memory");  // Ak0,Bk0 landed
        SCHED0(); BAR();

        for (int t = 0; t < 36; ++t) {
            const int cur = t & 1;
            ushort* Ak0 = LDS + cur * 32768;
            ushort* Ak1 = Ak0 + 8192;
            ushort* Bk0 = Ak0 + 16384;
            ushort* Bk1 = Ak0 + 24576;
            ushort* nA0 = LDS + (cur ^ 1) * 32768;
            ushort* nA1 = nA0 + 8192;
            ushort* nB0 = nA0 + 16384;
            ushort* nB1 = nA0 + 24576;
            const bool st = (t < 35);
            const int t1 = t + 1;
            const int seg1 = (t1 >= 24) ? 2 : ((t1 >= 12) ? 1 : 0);
            const int c1 = (t1 - seg1 * 12) * 64;
            const ushort* XA1 = (seg1 == 1) ? xl : xh;
            const ushort* XB1 = (seg1 == 2) ? xl : xh;

            bf16x8 avA[4], avB[4], bv[4];
            // ---- P1: read A(f0-3,ks0)+B(ks0); stage Ak0(t+1); MFMA f0-3 ks0
#pragma unroll
            for (int f = 0; f < 4; ++f) avA[f] = *(const bf16x8*)(Ak0 + aoff + f * 512);
#pragma unroll
            for (int n = 0; n < 4; ++n) bv[n] = *(const bf16x8*)(Bk0 + boff + n * 512);
            if (st) { gload16(XA1 + gA0 + c1, nA0 + ld0); gload16(XA1 + gA1 + c1, nA0 + ld1); }
            SCHED0(); BAR(); SCHED0();
            __builtin_amdgcn_s_setprio(1);
#pragma unroll
            for (int f = 0; f < 4; ++f)
#pragma unroll
                for (int n = 0; n < 4; ++n)
                    acc[f][n] = __builtin_amdgcn_mfma_f32_16x16x32_bf16(avA[f], bv[n], acc[f][n], 0, 0, 0);
            __builtin_amdgcn_s_setprio(0);
            SCHED0(); BAR();
            // ---- P2: read A(f4-7,ks0); stage Bk0(t+1); MFMA f4-7 ks0; vmcnt
#pragma unroll
            for (int f = 0; f < 4; ++f) avB[f] = *(const bf16x8*)(Ak0 + aoff + 2048 + f * 512);
            if (st) { gload16(XB1 + gB0 + c1, nB0 + ld0); gload16(XB1 + gB1 + c1, nB0 + ld1); }
            SCHED0(); BAR(); SCHED0();
            __builtin_amdgcn_s_setprio(1);
#pragma unroll
            for (int f = 0; f < 4; ++f)
#pragma unroll
                for (int n = 0; n < 4; ++n)
                    acc[4 + f][n] = __builtin_amdgcn_mfma_f32_16x16x32_bf16(avB[f], bv[n], acc[4 + f][n], 0, 0, 0);
            __builtin_amdgcn_s_setprio(0);
            if (st) { asm volatile("s_waitcnt vmcnt(4)" ::: "memory"); }  // Ak1,Bk1(t) landed
            else    { asm volatile("s_waitcnt vmcnt(0)" ::: "memory"); }
            SCHED0(); BAR();
            // ---- P3: read A(f0-3,ks1)+B(ks1); stage Ak1(t+1); MFMA f0-3 ks1
#pragma unroll
            for (int f = 0; f < 4; ++f) avA[f] = *(const bf16x8*)(Ak1 + aoff + f * 512);
#pragma unroll
            for (int n = 0; n < 4; ++n) bv[n] = *(const bf16x8*)(Bk1 + boff + n * 512);
            if (st) { gload16(XA1 + gA0 + c1 + 32, nA1 + ld0); gload16(XA1 + gA1 + c1 + 32, nA1 + ld1); }
            SCHED0(); BAR(); SCHED0();
            __builtin_amdgcn_s_setprio(1);
#pragma unroll
            for (int f = 0; f < 4; ++f)
#pragma unroll
                for (int n = 0; n < 4; ++n)
                    acc[f][n] = __builtin_amdgcn_mfma_f32_16x16x32_bf16(avA[f], bv[n], acc[f][n], 0, 0, 0);
            __builtin_amdgcn_s_setprio(0);
            SCHED0(); BAR();
            // ---- P4: read A(f4-7,ks1); stage Bk1(t+1); MFMA f4-7 ks1; vmcnt
#pragma unroll
            for (int f = 0; f < 4; ++f) avB[f] = *(const bf16x8*)(Ak1 + aoff + 2048 + f * 512);
            if (st) { gload16(XB1 + gB0 + c1 + 32, nB1 + ld0); gload16(XB1 + gB1 + c1 + 32, nB1 + ld1); }
            SCHED0(); BAR(); SCHED0();
            __builtin_amdgcn_s_setprio(1);
#pragma unroll
            for (int f = 0; f < 4; ++f)
#pragma unroll
                for (int n = 0; n < 4; ++n)
                    acc[4 + f][n] = __builtin_amdgcn_mfma_f32_16x16x32_bf16(avB[f], bv[n], acc[4 + f][n], 0, 0, 0);
            __builtin_amdgcn_s_setprio(0);
            if (st) { asm volatile("s_waitcnt vmcnt(4)" ::: "memory"); }  // Ak0,Bk0(t+1) landed
            SCHED0(); BAR();
        }

        // epilogue: cube, skip diag, per-row reductions
        const bool dblk = (bi == bj);
        float rsum[8][4], csum[4];
#pragma unroll
        for (int n = 0; n < 4; ++n) csum[n] = 0.f;
#pragma unroll
        for (int f = 0; f < 8; ++f)
#pragma unroll
            for (int r = 0; r < 4; ++r) rsum[f][r] = 0.f;
#pragma unroll
        for (int f = 0; f < 8; ++f)
#pragma unroll
            for (int n = 0; n < 4; ++n)
#pragma unroll
                for (int r = 0; r < 4; ++r) {
                    float s = acc[f][n][r];
                    float c = s * s * s;
                    int ri = wm * 128 + f * 16 + li4 * 4 + r;
                    int cj = wn * 64 + n * 16 + l15;
                    if (dblk && ri == cj) c = 0.f;
                    rsum[f][r] += c;
                    csum[n] += c;
                }
#pragma unroll
        for (int o = 1; o < 16; o <<= 1)
#pragma unroll
            for (int f = 0; f < 8; ++f)
#pragma unroll
                for (int r = 0; r < 4; ++r)
                    rsum[f][r] += __shfl_xor(rsum[f][r], o, 64);
        if (l15 == 0) {
#pragma unroll
            for (int f = 0; f < 8; ++f)
#pragma unroll
                for (int r = 0; r < 4; ++r)
                    atomicAdd(&rc[bi * 256 + wm * 128 + f * 16 + li4 * 4 + r], rsum[f][r]);
        }
        if (!dblk) {
#pragma unroll
            for (int o = 16; o < 64; o <<= 1)
#pragma unroll
                for (int n = 0; n < 4; ++n) csum[n] += __shfl_xor(csum[n], o, 64);
            if (li4 == 0) {
#pragma unroll
                for (int n = 0; n < 4; ++n)
                    atomicAdd(&rc[bj * 256 + wn * 64 + n * 16 + l15], csum[n]);
            }
        }
    } else {
        // ---- quarter tile: 128x128, full K. qi=q>>1, qj=q&1 ----
        const int qi = q >> 1, qj = q & 1;
        const int gr = bi * 2 + qi, gc = bj * 2 + qj;
        if (gc < gr) return;  // redundant lower quarter of a diagonal parent
        const int R0 = gr * 128, C0 = gc * 128;
        const int wm = wid >> 2, wn = wid & 3;  // per-wave 64x32
        const int aoff = (wm * 64 + l15) * 32 + li4 * 8;
        const int boff = (wn * 32 + l15) * 32 + li4 * 8;
        const int gA0 = (R0 + (tid >> 2)) * DD + (tid & 3) * 8;
        const int gB0 = (C0 + (tid >> 2)) * DD + (tid & 3) * 8;
        const int ld0 = tid * 8;

        f32x4 acc[4][2];
#pragma unroll
        for (int f = 0; f < 4; ++f)
#pragma unroll
            for (int n = 0; n < 2; ++n) acc[f][n] = (f32x4){0.f, 0.f, 0.f, 0.f};

        // prologue tile 0
        gload16(xh + gA0, LDS + ld0);
        gload16(xh + gB0, LDS + 8192 + ld0);
        gload16(xh + gA0 + 32, LDS + 4096 + ld0);
        gload16(xh + gB0 + 32, LDS + 12288 + ld0);
        asm volatile("s_waitcnt vmcnt(0)" ::: "memory");
        SCHED0(); BAR();

        for (int t = 0; t < 36; ++t) {
            const int cur = t & 1;
            ushort* A0 = LDS + cur * 16384;
            ushort* A1 = A0 + 4096;
            ushort* B0 = A0 + 8192;
            ushort* B1 = A0 + 12288;
            ushort* nA0 = LDS + (cur ^ 1) * 16384;
            const bool st = (t < 35);
            const int t1 = t + 1;
            const int seg1 = (t1 >= 24) ? 2 : ((t1 >= 12) ? 1 : 0);
            const int c1 = (t1 - seg1 * 12) * 64;
            const ushort* XA1 = (seg1 == 1) ? xl : xh;
            const ushort* XB1 = (seg1 == 2) ? xl : xh;

            bf16x8 av0[4], av1[4], bv0[2], bv1[2];
#pragma unroll
            for (int f = 0; f < 4; ++f) {
                av0[f] = *(const bf16x8*)(A0 + aoff + f * 512);
                av1[f] = *(const bf16x8*)(A1 + aoff + f * 512);
            }
#pragma unroll
            for (int n = 0; n < 2; ++n) {
                bv0[n] = *(const bf16x8*)(B0 + boff + n * 512);
                bv1[n] = *(const bf16x8*)(B1 + boff + n * 512);
            }
            if (st) {
                gload16(XA1 + gA0 + c1, nA0 + ld0);
                gload16(XB1 + gB0 + c1, nA0 + 8192 + ld0);
                gload16(XA1 + gA0 + c1 + 32, nA0 + 4096 + ld0);
                gload16(XB1 + gB0 + c1 + 32, nA0 + 12288 + ld0);
            }
            __builtin_amdgcn_s_setprio(1);
#pragma unroll
            for (int f = 0; f < 4; ++f)
#pragma unroll
                for (int n = 0; n < 2; ++n)
                    acc[f][n] = __builtin_amdgcn_mfma_f32_16x16x32_bf16(av0[f], bv0[n], acc[f][n], 0, 0, 0);
#pragma unroll
            for (int f = 0; f < 4; ++f)
#pragma unroll
                for (int n = 0; n < 2; ++n)
                    acc[f][n] = __builtin_amdgcn_mfma_f32_16x16x32_bf16(av1[f], bv1[n], acc[f][n], 0, 0, 0);
            __builtin_amdgcn_s_setprio(0);
            asm volatile("s_waitcnt vmcnt(0)" ::: "memory");
            SCHED0(); BAR();
        }

        const bool dblk = (gr == gc);
        float rsum[4][4], csum[2];
#pragma unroll
        for (int n = 0; n < 2; ++n) csum[n] = 0.f;
#pragma unroll
        for (int f = 0; f < 4; ++f)
#pragma unroll
            for (int r = 0; r < 4; ++r) rsum[f][r] = 0.f;
#pragma unroll
        for (int f = 0; f < 4; ++f)
#pragma unroll
            for (int n = 0; n < 2; ++n)
#pragma unroll
                for (int r = 0; r < 4; ++r) {
                    float s = acc[f][n][r];
                    float c = s * s * s;
                    int ri = wm * 64 + f * 16 + li4 * 4 + r;
                    int cj = wn * 32 + n * 16 + l15;
                    if (dblk && ri == cj) c = 0.f;
                    rsum[f][r] += c;
                    csum[n] += c;
                }
#pragma unroll
        for (int o = 1; o < 16; o <<= 1)
#pragma unroll
            for (int f = 0; f < 4; ++f)
#pragma unroll
                for (int r = 0; r < 4; ++r)
                    rsum[f][r] += __shfl_xor(rsum[f][r], o, 64);
        if (l15 == 0) {
#pragma unroll
            for (int f = 0; f < 4; ++f)
#pragma unroll
                for (int r = 0; r < 4; ++r)
                    atomicAdd(&rc[R0 + wm * 64 + f * 16 + li4 * 4 + r], rsum[f][r]);
        }
        if (!dblk) {
#pragma unroll
            for (int o = 16; o < 64; o <<= 1)
#pragma unroll
                for (int n = 0; n < 2; ++n) csum[n] += __shfl_xor(csum[n], o, 64);
            if (li4 == 0) {
#pragma unroll
                for (int n = 0; n < 2; ++n)
                    atomicAdd(&rc[C0 + wn * 32 + n * 16 + l15], csum[n]);
            }
        }
    }
}

// ---------------------------------------------------------------------------
// k_final: out = collapse + 0.2 * sum_i rc_i / (mnum_i/8191 + 1e-6)
// ---------------------------------------------------------------------------
__global__ __launch_bounds__(256) void k_final(const float* __restrict__ rc,
                                               const double* __restrict__ mnum,
                                               const double* __restrict__ dd,
                                               float* __restrict__ out) {
    int tid = threadIdx.x;
    double acc = 0.0, col = 0.0;
    for (int r = tid; r < VV; r += 256) {
        double m = mnum[r] / 8191.0 + 1e-6;
        acc += (double)rc[r] / m;
        double dm = dd[r] - 1.0;
        col += dm * dm;
    }
    __shared__ double sa[256], sc[256];
    sa[tid] = acc;
    sc[tid] = col;
    __syncthreads();
    for (int o = 128; o > 0; o >>= 1) {
        if (tid < o) {
            sa[tid] += sa[tid + o];
            sc[tid] += sc[tid + o];
        }
        __syncthreads();
    }
    if (tid == 0) out[0] = (float)(sc[0] + 0.2 * sa[0]);
}

// ---------------------------------------------------------------------------
extern "C" void kernel_launch(void* const* d_in, const int* in_sizes, int n_in,
                              void* d_out, int out_size, void* d_ws, size_t ws_size,
                              hipStream_t stream) {
    const float* t = (const float*)d_in[0];
    float* out = (float*)d_out;

    char* ws = (char*)d_ws;
    float* x = (float*)ws;
    size_t off = (size_t)VV * DD * sizeof(float);           // 25.2 MB
    ushort* xh = (ushort*)(ws + off); off += (size_t)VV * DD * sizeof(ushort);
    ushort* xl = (ushort*)(ws + off); off += (size_t)VV * DD * sizeof(ushort);
    double* g = (double*)(ws + off);  off += DD * sizeof(double);
    double* mnum = (double*)(ws + off); off += VV * sizeof(double);
    double* dd = (double*)(ws + off);  off += VV * sizeof(double);
    float* rc = (float*)(ws + off);    off += VV * sizeof(float);

    hipMemsetAsync(g, 0, DD * sizeof(double), stream);
    hipMemsetAsync(rc, 0, VV * sizeof(float), stream);

    k_normpack<<<VV, 256, 0, stream>>>(t, x, xh, xl);
    k_colsum<<<256, 256, 0, stream>>>(x, g);
    k_mean<<<VV / 4, 256, 0, stream>>>(x, g, mnum, dd);
    k_cube<<<576, 512, 0, stream>>>(xh, xl, rc);
    k_final<<<1, 256, 0, stream>>>(rc, mnum, dd, out);
}

// Round 5
// 186.886 us; speedup vs baseline: 4.3485x; 1.2856x over previous
//
#include <hip/hip_runtime.h>
#include <math.h>

#define VV 8192
#define DD 768
#define NDMAX 256

typedef __attribute__((ext_vector_type(8))) short bf16x8;
typedef __attribute__((ext_vector_type(4))) float f32x4;

// RNE float -> bf16 bits
__device__ inline ushort f2bf(float f) {
    uint u = __float_as_uint(f);
    uint r = (u + 0x7fffu + ((u >> 16) & 1u)) >> 16;
    return (ushort)r;
}
__device__ inline float bf2f(ushort h) { return __uint_as_float(((uint)h) << 16); }

__device__ inline void gload16(const ushort* g, ushort* l) {
    __builtin_amdgcn_global_load_lds(
        (const __attribute__((address_space(1))) void*)g,
        (__attribute__((address_space(3))) void*)l, 16, 0, 0);
}
#define BAR() asm volatile("s_barrier" ::: "memory")
#define SCHED0() __builtin_amdgcn_sched_barrier(0)

// ---------------------------------------------------------------------------
// k_normpack: L2-normalize rows (fp64 norm accum) -> x (fp32), xh/xl (bf16
// hi/lo split; xl used only by the correction strip).
// ---------------------------------------------------------------------------
__global__ __launch_bounds__(256) void k_normpack(const float* __restrict__ t,
                                                  float* __restrict__ x,
                                                  ushort* __restrict__ xh,
                                                  ushort* __restrict__ xl) {
    int r = blockIdx.x;
    const float* tr = t + (size_t)r * DD;
    int tid = threadIdx.x;
    float v0 = tr[tid], v1 = tr[tid + 256], v2 = tr[tid + 512];
    double s = (double)v0 * v0 + (double)v1 * v1 + (double)v2 * v2;
#pragma unroll
    for (int o = 32; o > 0; o >>= 1) s += __shfl_down(s, o, 64);
    __shared__ double wsum[4];
    int lane = tid & 63, w = tid >> 6;
    if (lane == 0) wsum[w] = s;
    __syncthreads();
    double tot = wsum[0] + wsum[1] + wsum[2] + wsum[3];
    float norm = fmaxf((float)sqrt(tot), 1e-12f);
    size_t base = (size_t)r * DD;
#pragma unroll
    for (int q = 0; q < 3; ++q) {
        int k = tid + q * 256;
        float v = (q == 0 ? v0 : (q == 1 ? v1 : v2)) / norm;
        x[base + k] = v;
        ushort h = f2bf(v);
        xh[base + k] = h;
        xl[base + k] = f2bf(v - bf2f(h));
    }
}

// ---------------------------------------------------------------------------
// k_colsum: g[k] = sum over rows of x[r][k], fp64.
// ---------------------------------------------------------------------------
__global__ __launch_bounds__(256) void k_colsum(const float* __restrict__ x,
                                                double* __restrict__ g) {
    int t = threadIdx.x;
    int r0 = blockIdx.x * 32;
    double s0 = 0.0, s1 = 0.0, s2 = 0.0;
    for (int r = r0; r < r0 + 32; ++r) {
        const float* xr = x + (size_t)r * DD;
        s0 += (double)xr[t];
        s1 += (double)xr[t + 256];
        s2 += (double)xr[t + 512];
    }
    atomicAdd(&g[t], s0);
    atomicAdd(&g[t + 256], s1);
    atomicAdd(&g[t + 512], s2);
}

// ---------------------------------------------------------------------------
// k_mean: mnum[r] = x_r.g - x_r.x_r (fp64); dd[r] = x_r.x_r (S diagonal).
// Exact mean path -- numerically deadly, do not approximate.
// ---------------------------------------------------------------------------
__global__ __launch_bounds__(256) void k_mean(const float* __restrict__ x,
                                              const double* __restrict__ g,
                                              double* __restrict__ mnum,
                                              double* __restrict__ dd) {
    int r = blockIdx.x * 4 + (threadIdx.x >> 6);
    int lane = threadIdx.x & 63;
    const float* xr = x + (size_t)r * DD;
    double xg = 0.0, xx = 0.0;
#pragma unroll
    for (int k = lane; k < DD; k += 64) {
        double xv = (double)xr[k];
        xg += xv * g[k];
        xx += xv * xv;
    }
#pragma unroll
    for (int o = 32; o > 0; o >>= 1) {
        xg += __shfl_down(xg, o, 64);
        xx += __shfl_down(xx, o, 64);
    }
    if (lane == 0) {
        mnum[r] = xg - xx;
        dd[r] = xx;
    }
}

// ---------------------------------------------------------------------------
// k_select: deterministic, row-sorted compaction of "danger" rows --
// |mean_neg + eps| < 1e-5, whose hard-neg ratio amplifies cube-path error.
// These get the exact 3-term treatment in the strip pass.
// ---------------------------------------------------------------------------
__global__ __launch_bounds__(256) void k_select(const double* __restrict__ mnum,
                                                int* __restrict__ dlist) {
    __shared__ int cnts[256];
    int tid = threadIdx.x;
    int r0 = tid * 32;
    int c = 0;
    for (int i = 0; i < 32; ++i) {
        double md = fabs(mnum[r0 + i] / 8191.0 + 1e-6);
        if (md < 1e-5) ++c;
    }
    cnts[tid] = c;
    __syncthreads();
    int pre = 0;
    for (int i = 0; i < tid; ++i) pre += cnts[i];
    for (int i = 0; i < 32; ++i) {
        int r = r0 + i;
        double md = fabs(mnum[r] / 8191.0 + 1e-6);
        if (md < 1e-5) {
            if (pre < NDMAX) dlist[pre] = r;
            ++pre;
        }
    }
}

// ---------------------------------------------------------------------------
// strip epilogue helper: per-row cube sums (row side only), signed atomics.
// ---------------------------------------------------------------------------
__device__ __forceinline__ void strip_epi(const f32x4 (&acc)[8][4], const int* dsh,
                                          int bjs, int wm, int wn, int l15,
                                          int li4, float sign,
                                          float* __restrict__ rc) {
#pragma unroll
    for (int f = 0; f < 8; ++f) {
        float rs[4] = {0.f, 0.f, 0.f, 0.f};
#pragma unroll
        for (int r = 0; r < 4; ++r) {
            int drow = dsh[wm * 128 + f * 16 + li4 * 4 + r];
#pragma unroll
            for (int n = 0; n < 4; ++n) {
                float s = acc[f][n][r];
                float c = s * s * s;
                int colg = bjs * 256 + wn * 64 + n * 16 + l15;
                if (drow < 0 || colg == drow) c = 0.f;
                rs[r] += c;
            }
        }
#pragma unroll
        for (int o = 1; o < 16; o <<= 1)
#pragma unroll
            for (int r = 0; r < 4; ++r) rs[r] += __shfl_xor(rs[r], o, 64);
        if (l15 == 0) {
#pragma unroll
            for (int r = 0; r < 4; ++r) {
                int drow = dsh[wm * 128 + f * 16 + li4 * 4 + r];
                if (drow >= 0) atomicAdd(&rc[drow], sign * rs[r]);
            }
        }
    }
}

// ---------------------------------------------------------------------------
// k_cube: two-tier bf16 MFMA pass.
//  - bids 0..31: STRIP blocks (dispatched first, 3x duration): danger rows
//    (<=256, gathered) x all 8192 cols, 36 K-tiles (hh + lo.hi + hi.lo);
//    atomically subtract hh-cube (after tile 12) and add 3-term cube.
//  - bids 32..543: big 256^2 triangle tiles, 12 K-tiles (hh only),
//    XCD-bijective swizzle; row+col cube sums via symmetry.
//  - bids 544..607: quarter tiles (128^2) of the last 16 triangle tiles.
// LDS: k-half arrays [rows][32] bf16, slot XOR-swizzle p = li4^((l15>>1)&3)
// (2 words/bank per 16-lane b128 phase = conflict-free); staged via
// global_load_lds w=16 with pre-swizzled per-lane source, linear dest.
// 4-phase schedule per K-tile, counted vmcnt(4), raw barriers, setprio.
// ---------------------------------------------------------------------------
__global__ __launch_bounds__(512, 2) void k_cube(const ushort* __restrict__ xh,
                                                 const ushort* __restrict__ xl,
                                                 const int* __restrict__ dlist,
                                                 float* __restrict__ rc) {
    __shared__ ushort LDS[65536];  // 128 KiB
    __shared__ int dsh[NDMAX];

    const int bid = blockIdx.x;
    const int tid = threadIdx.x;
    const int lane = tid & 63;
    const int wid = tid >> 6;
    const int l15 = lane & 15, li4 = lane >> 4;
    const int swzrd = ((li4 ^ ((l15 >> 1) & 3)) << 3);  // read slot (ushorts)

    if (bid >= 544) {
        // ---- quarter tile: 128x128, K=768 (hh only) ----
        const int qid = bid - 544;
        int wg = 512 + (qid >> 2), q = qid & 3;
        int bi = 0, rem = wg;
        while (rem >= 32 - bi) { rem -= 32 - bi; ++bi; }
        const int bj = bi + rem;
        const int gr = bi * 2 + (q >> 1), gc = bj * 2 + (q & 1);
        if (gc < gr) return;
        const int R0 = gr * 128, C0 = gc * 128;
        const int wm = wid >> 2, wn = wid & 3;  // per-wave 64x32
        const int aoff = (wm * 64 + l15) * 32 + swzrd;
        const int boff = (wn * 32 + l15) * 32 + swzrd;
        const int sl = ((tid & 3) ^ ((tid >> 3) & 3)) * 8;  // staging src slot
        const int gA0 = (R0 + (tid >> 2)) * DD + sl;
        const int gB0 = (C0 + (tid >> 2)) * DD + sl;
        const int ld0 = tid * 8;

        f32x4 acc[4][2];
#pragma unroll
        for (int f = 0; f < 4; ++f)
#pragma unroll
            for (int n = 0; n < 2; ++n) acc[f][n] = (f32x4){0.f, 0.f, 0.f, 0.f};

        gload16(xh + gA0, LDS + ld0);
        gload16(xh + gB0, LDS + 8192 + ld0);
        gload16(xh + gA0 + 32, LDS + 4096 + ld0);
        gload16(xh + gB0 + 32, LDS + 12288 + ld0);
        asm volatile("s_waitcnt vmcnt(0)" ::: "memory");
        SCHED0(); BAR();

        for (int t = 0; t < 12; ++t) {
            const int cur = t & 1;
            ushort* A0 = LDS + cur * 16384;
            ushort* A1 = A0 + 4096;
            ushort* B0 = A0 + 8192;
            ushort* B1 = A0 + 12288;
            ushort* nA0 = LDS + (cur ^ 1) * 16384;
            const bool st = (t < 11);
            const int c1 = (t + 1) * 64;

            bf16x8 av0[4], av1[4], bv0[2], bv1[2];
#pragma unroll
            for (int f = 0; f < 4; ++f) {
                av0[f] = *(const bf16x8*)(A0 + aoff + f * 512);
                av1[f] = *(const bf16x8*)(A1 + aoff + f * 512);
            }
#pragma unroll
            for (int n = 0; n < 2; ++n) {
                bv0[n] = *(const bf16x8*)(B0 + boff + n * 512);
                bv1[n] = *(const bf16x8*)(B1 + boff + n * 512);
            }
            if (st) {
                gload16(xh + gA0 + c1, nA0 + ld0);
                gload16(xh + gB0 + c1, nA0 + 8192 + ld0);
                gload16(xh + gA0 + c1 + 32, nA0 + 4096 + ld0);
                gload16(xh + gB0 + c1 + 32, nA0 + 12288 + ld0);
            }
            __builtin_amdgcn_s_setprio(1);
#pragma unroll
            for (int f = 0; f < 4; ++f)
#pragma unroll
                for (int n = 0; n < 2; ++n)
                    acc[f][n] = __builtin_amdgcn_mfma_f32_16x16x32_bf16(av0[f], bv0[n], acc[f][n], 0, 0, 0);
#pragma unroll
            for (int f = 0; f < 4; ++f)
#pragma unroll
                for (int n = 0; n < 2; ++n)
                    acc[f][n] = __builtin_amdgcn_mfma_f32_16x16x32_bf16(av1[f], bv1[n], acc[f][n], 0, 0, 0);
            __builtin_amdgcn_s_setprio(0);
            asm volatile("s_waitcnt vmcnt(0)" ::: "memory");
            SCHED0(); BAR();
        }

        const bool dblk = (gr == gc);
        float rsum[4][4], csum[2];
#pragma unroll
        for (int n = 0; n < 2; ++n) csum[n] = 0.f;
#pragma unroll
        for (int f = 0; f < 4; ++f)
#pragma unroll
            for (int r = 0; r < 4; ++r) rsum[f][r] = 0.f;
#pragma unroll
        for (int f = 0; f < 4; ++f)
#pragma unroll
            for (int n = 0; n < 2; ++n)
#pragma unroll
                for (int r = 0; r < 4; ++r) {
                    float s = acc[f][n][r];
                    float c = s * s * s;
                    int ri = wm * 64 + f * 16 + li4 * 4 + r;
                    int cj = wn * 32 + n * 16 + l15;
                    if (dblk && ri == cj) c = 0.f;
                    rsum[f][r] += c;
                    csum[n] += c;
                }
#pragma unroll
        for (int o = 1; o < 16; o <<= 1)
#pragma unroll
            for (int f = 0; f < 4; ++f)
#pragma unroll
                for (int r = 0; r < 4; ++r)
                    rsum[f][r] += __shfl_xor(rsum[f][r], o, 64);
        if (l15 == 0) {
#pragma unroll
            for (int f = 0; f < 4; ++f)
#pragma unroll
                for (int r = 0; r < 4; ++r)
                    atomicAdd(&rc[R0 + wm * 64 + f * 16 + li4 * 4 + r], rsum[f][r]);
        }
        if (!dblk) {
#pragma unroll
            for (int o = 16; o < 64; o <<= 1)
#pragma unroll
                for (int n = 0; n < 2; ++n) csum[n] += __shfl_xor(csum[n], o, 64);
            if (li4 == 0) {
#pragma unroll
                for (int n = 0; n < 2; ++n)
                    atomicAdd(&rc[C0 + wn * 32 + n * 16 + l15], csum[n]);
            }
        }
        return;
    }

    // ---- shared 256x256 path: strip (bid<32) or big (bid-32 in [0,512)) ----
    const bool strip = (bid < 32);
    const int nt = strip ? 36 : 12;
    int bi = 0, bj = 0, bjs = 0;
    if (strip) {
        bjs = bid;
        if (tid < NDMAX) dsh[tid] = dlist[tid];
    } else {
        const int idx = bid - 32;
        int wg = (idx & 7) * 64 + (idx >> 3);
        int rem = wg;
        while (rem >= 32 - bi) { rem -= 32 - bi; ++bi; }
        bj = bi + rem;
    }
    const int wm = wid >> 2, wn = wid & 3;  // 2M x 4N, per-wave 128x64
    const int aoff = (wm * 128 + l15) * 32 + swzrd;
    const int boff = (wn * 64 + l15) * 32 + swzrd;

    const int li0 = tid, li1 = tid + 512;
    const int sl0 = ((li0 & 3) ^ ((li0 >> 3) & 3)) * 8;
    const int sl1 = ((li1 & 3) ^ ((li1 >> 3) & 3)) * 8;
    int ar0, ar1;
    if (strip) {
        ar0 = dlist[li0 >> 2];
        ar1 = dlist[li1 >> 2];
        if (ar0 < 0) ar0 = 0;
        if (ar1 < 0) ar1 = 0;
    } else {
        ar0 = bi * 256 + (li0 >> 2);
        ar1 = bi * 256 + (li1 >> 2);
    }
    const int bt = strip ? bjs : bj;
    const int gA0 = ar0 * DD + sl0;
    const int gA1 = ar1 * DD + sl1;
    const int gB0 = (bt * 256 + (li0 >> 2)) * DD + sl0;
    const int gB1 = (bt * 256 + (li1 >> 2)) * DD + sl1;
    const int ld0 = li0 * 8, ld1 = li1 * 8;

    f32x4 acc[8][4];
#pragma unroll
    for (int f = 0; f < 8; ++f)
#pragma unroll
        for (int n = 0; n < 4; ++n) acc[f][n] = (f32x4){0.f, 0.f, 0.f, 0.f};

    // prologue: stage tile 0 (hh), order Ak0,Bk0,Ak1,Bk1
    gload16(xh + gA0, LDS + ld0);              gload16(xh + gA1, LDS + ld1);
    gload16(xh + gB0, LDS + 16384 + ld0);      gload16(xh + gB1, LDS + 16384 + ld1);
    gload16(xh + gA0 + 32, LDS + 8192 + ld0);  gload16(xh + gA1 + 32, LDS + 8192 + ld1);
    gload16(xh + gB0 + 32, LDS + 24576 + ld0); gload16(xh + gB1 + 32, LDS + 24576 + ld1);
    asm volatile("s_waitcnt vmcnt(4)" ::: "memory");
    SCHED0(); BAR();

    for (int t = 0; t < nt; ++t) {
        if (strip && t == 12)  // hh complete: subtract hh-cube for danger rows
            strip_epi(acc, dsh, bjs, wm, wn, l15, li4, -1.f, rc);

        const int cur = t & 1;
        ushort* Ak0 = LDS + cur * 32768;
        ushort* Ak1 = Ak0 + 8192;
        ushort* Bk0 = Ak0 + 16384;
        ushort* Bk1 = Ak0 + 24576;
        ushort* nA0 = LDS + (cur ^ 1) * 32768;
        ushort* nA1 = nA0 + 8192;
        ushort* nB0 = nA0 + 16384;
        ushort* nB1 = nA0 + 24576;
        const bool st = (t < nt - 1);
        const int t1 = t + 1;
        const int seg1 = (t1 >= 24) ? 2 : ((t1 >= 12) ? 1 : 0);
        const int c1 = (t1 - seg1 * 12) * 64;
        const ushort* XA1 = (seg1 == 1) ? xl : xh;
        const ushort* XB1 = (seg1 == 2) ? xl : xh;

        bf16x8 avA[4], avB[4], bv[4];
        // ---- P1: read A(f0-3,ks0)+B(ks0); stage Ak0(t+1); MFMA f0-3 ks0
#pragma unroll
        for (int f = 0; f < 4; ++f) avA[f] = *(const bf16x8*)(Ak0 + aoff + f * 512);
#pragma unroll
        for (int n = 0; n < 4; ++n) bv[n] = *(const bf16x8*)(Bk0 + boff + n * 512);
        if (st) { gload16(XA1 + gA0 + c1, nA0 + ld0); gload16(XA1 + gA1 + c1, nA0 + ld1); }
        SCHED0(); BAR(); SCHED0();
        __builtin_amdgcn_s_setprio(1);
#pragma unroll
        for (int f = 0; f < 4; ++f)
#pragma unroll
            for (int n = 0; n < 4; ++n)
                acc[f][n] = __builtin_amdgcn_mfma_f32_16x16x32_bf16(avA[f], bv[n], acc[f][n], 0, 0, 0);
        __builtin_amdgcn_s_setprio(0);
        SCHED0(); BAR();
        // ---- P2: read A(f4-7,ks0); stage Bk0(t+1); MFMA f4-7 ks0; vmcnt
#pragma unroll
        for (int f = 0; f < 4; ++f) avB[f] = *(const bf16x8*)(Ak0 + aoff + 2048 + f * 512);
        if (st) { gload16(XB1 + gB0 + c1, nB0 + ld0); gload16(XB1 + gB1 + c1, nB0 + ld1); }
        SCHED0(); BAR(); SCHED0();
        __builtin_amdgcn_s_setprio(1);
#pragma unroll
        for (int f = 0; f < 4; ++f)
#pragma unroll
            for (int n = 0; n < 4; ++n)
                acc[4 + f][n] = __builtin_amdgcn_mfma_f32_16x16x32_bf16(avB[f], bv[n], acc[4 + f][n], 0, 0, 0);
        __builtin_amdgcn_s_setprio(0);
        if (st) { asm volatile("s_waitcnt vmcnt(4)" ::: "memory"); }
        else    { asm volatile("s_waitcnt vmcnt(0)" ::: "memory"); }
        SCHED0(); BAR();
        // ---- P3: read A(f0-3,ks1)+B(ks1); stage Ak1(t+1); MFMA f0-3 ks1
#pragma unroll
        for (int f = 0; f < 4; ++f) avA[f] = *(const bf16x8*)(Ak1 + aoff + f * 512);
#pragma unroll
        for (int n = 0; n < 4; ++n) bv[n] = *(const bf16x8*)(Bk1 + boff + n * 512);
        if (st) { gload16(XA1 + gA0 + c1 + 32, nA1 + ld0); gload16(XA1 + gA1 + c1 + 32, nA1 + ld1); }
        SCHED0(); BAR(); SCHED0();
        __builtin_amdgcn_s_setprio(1);
#pragma unroll
        for (int f = 0; f < 4; ++f)
#pragma unroll
            for (int n = 0; n < 4; ++n)
                acc[f][n] = __builtin_amdgcn_mfma_f32_16x16x32_bf16(avA[f], bv[n], acc[f][n], 0, 0, 0);
        __builtin_amdgcn_s_setprio(0);
        SCHED0(); BAR();
        // ---- P4: read A(f4-7,ks1); stage Bk1(t+1); MFMA f4-7 ks1; vmcnt
#pragma unroll
        for (int f = 0; f < 4; ++f) avB[f] = *(const bf16x8*)(Ak1 + aoff + 2048 + f * 512);
        if (st) { gload16(XB1 + gB0 + c1 + 32, nB1 + ld0); gload16(XB1 + gB1 + c1 + 32, nB1 + ld1); }
        SCHED0(); BAR(); SCHED0();
        __builtin_amdgcn_s_setprio(1);
#pragma unroll
        for (int f = 0; f < 4; ++f)
#pragma unroll
            for (int n = 0; n < 4; ++n)
                acc[4 + f][n] = __builtin_amdgcn_mfma_f32_16x16x32_bf16(avB[f], bv[n], acc[4 + f][n], 0, 0, 0);
        __builtin_amdgcn_s_setprio(0);
        if (st) { asm volatile("s_waitcnt vmcnt(4)" ::: "memory"); }
        SCHED0(); BAR();
    }

    if (strip) {
        // 3-term complete: add 3-term cube for danger rows
        strip_epi(acc, dsh, bjs, wm, wn, l15, li4, 1.f, rc);
        return;
    }

    // big-tile epilogue: cube, skip diag, row + col (symmetry) sums
    const bool dblk = (bi == bj);
    float rsum[8][4], csum[4];
#pragma unroll
    for (int n = 0; n < 4; ++n) csum[n] = 0.f;
#pragma unroll
    for (int f = 0; f < 8; ++f)
#pragma unroll
        for (int r = 0; r < 4; ++r) rsum[f][r] = 0.f;
#pragma unroll
    for (int f = 0; f < 8; ++f)
#pragma unroll
        for (int n = 0; n < 4; ++n)
#pragma unroll
            for (int r = 0; r < 4; ++r) {
                float s = acc[f][n][r];
                float c = s * s * s;
                int ri = wm * 128 + f * 16 + li4 * 4 + r;
                int cj = wn * 64 + n * 16 + l15;
                if (dblk && ri == cj) c = 0.f;
                rsum[f][r] += c;
                csum[n] += c;
            }
#pragma unroll
    for (int o = 1; o < 16; o <<= 1)
#pragma unroll
        for (int f = 0; f < 8; ++f)
#pragma unroll
            for (int r = 0; r < 4; ++r)
                rsum[f][r] += __shfl_xor(rsum[f][r], o, 64);
    if (l15 == 0) {
#pragma unroll
        for (int f = 0; f < 8; ++f)
#pragma unroll
            for (int r = 0; r < 4; ++r)
                atomicAdd(&rc[bi * 256 + wm * 128 + f * 16 + li4 * 4 + r], rsum[f][r]);
    }
    if (!dblk) {
#pragma unroll
        for (int o = 16; o < 64; o <<= 1)
#pragma unroll
            for (int n = 0; n < 4; ++n) csum[n] += __shfl_xor(csum[n], o, 64);
        if (li4 == 0) {
#pragma unroll
            for (int n = 0; n < 4; ++n)
                atomicAdd(&rc[bj * 256 + wn * 64 + n * 16 + l15], csum[n]);
        }
    }
}

// ---------------------------------------------------------------------------
// k_final: out = collapse + 0.2 * sum_i rc_i / (mnum_i/8191 + 1e-6)
// ---------------------------------------------------------------------------
__global__ __launch_bounds__(256) void k_final(const float* __restrict__ rc,
                                               const double* __restrict__ mnum,
                                               const double* __restrict__ dd,
                                               float* __restrict__ out) {
    int tid = threadIdx.x;
    double acc = 0.0, col = 0.0;
    for (int r = tid; r < VV; r += 256) {
        double m = mnum[r] / 8191.0 + 1e-6;
        acc += (double)rc[r] / m;
        double dm = dd[r] - 1.0;
        col += dm * dm;
    }
    __shared__ double sa[256], sc[256];
    sa[tid] = acc;
    sc[tid] = col;
    __syncthreads();
    for (int o = 128; o > 0; o >>= 1) {
        if (tid < o) {
            sa[tid] += sa[tid + o];
            sc[tid] += sc[tid + o];
        }
        __syncthreads();
    }
    if (tid == 0) out[0] = (float)(sc[0] + 0.2 * sa[0]);
}

// ---------------------------------------------------------------------------
extern "C" void kernel_launch(void* const* d_in, const int* in_sizes, int n_in,
                              void* d_out, int out_size, void* d_ws, size_t ws_size,
                              hipStream_t stream) {
    const float* t = (const float*)d_in[0];
    float* out = (float*)d_out;

    char* ws = (char*)d_ws;
    float* x = (float*)ws;
    size_t off = (size_t)VV * DD * sizeof(float);           // 25.2 MB
    ushort* xh = (ushort*)(ws + off); off += (size_t)VV * DD * sizeof(ushort);
    ushort* xl = (ushort*)(ws + off); off += (size_t)VV * DD * sizeof(ushort);
    double* g = (double*)(ws + off);  off += DD * sizeof(double);
    double* mnum = (double*)(ws + off); off += VV * sizeof(double);
    double* dd = (double*)(ws + off);  off += VV * sizeof(double);
    float* rc = (float*)(ws + off);    off += VV * sizeof(float);
    int* dlist = (int*)(ws + off);     off += NDMAX * sizeof(int);

    hipMemsetAsync(g, 0, DD * sizeof(double), stream);
    hipMemsetAsync(rc, 0, VV * sizeof(float), stream);
    hipMemsetAsync(dlist, 0xFF, NDMAX * sizeof(int), stream);

    k_normpack<<<VV, 256, 0, stream>>>(t, x, xh, xl);
    k_colsum<<<256, 256, 0, stream>>>(x, g);
    k_mean<<<VV / 4, 256, 0, stream>>>(x, g, mnum, dd);
    k_select<<<1, 256, 0, stream>>>(mnum, dlist);
    k_cube<<<608, 512, 0, stream>>>(xh, xl, dlist, rc);
    k_final<<<1, 256, 0, stream>>>(rc, mnum, dd, out);
}

// Round 6
// 171.915 us; speedup vs baseline: 4.7272x; 1.0871x over previous
//
#include <hip/hip_runtime.h>
#include <math.h>

#define VV 8192
#define DD 768
#define NDMAX 256

typedef __attribute__((ext_vector_type(8))) short bf16x8;
typedef __attribute__((ext_vector_type(4))) float f32x4;

// RNE float -> bf16 bits
__device__ inline ushort f2bf(float f) {
    uint u = __float_as_uint(f);
    uint r = (u + 0x7fffu + ((u >> 16) & 1u)) >> 16;
    return (ushort)r;
}
__device__ inline float bf2f(ushort h) { return __uint_as_float(((uint)h) << 16); }

__device__ inline void gload16(const ushort* g, ushort* l) {
    __builtin_amdgcn_global_load_lds(
        (const __attribute__((address_space(1))) void*)g,
        (__attribute__((address_space(3))) void*)l, 16, 0, 0);
}
#define BAR() asm volatile("s_barrier" ::: "memory")
#define SCHED0() __builtin_amdgcn_sched_barrier(0)

// ---------------------------------------------------------------------------
// k_normpack: L2-normalize rows (fp64 norm accum) -> x (fp32), xh/xl (bf16
// hi/lo split; xl used only by the correction segments).
// ---------------------------------------------------------------------------
__global__ __launch_bounds__(256) void k_normpack(const float* __restrict__ t,
                                                  float* __restrict__ x,
                                                  ushort* __restrict__ xh,
                                                  ushort* __restrict__ xl) {
    int r = blockIdx.x;
    const float* tr = t + (size_t)r * DD;
    int tid = threadIdx.x;
    float v0 = tr[tid], v1 = tr[tid + 256], v2 = tr[tid + 512];
    double s = (double)v0 * v0 + (double)v1 * v1 + (double)v2 * v2;
#pragma unroll
    for (int o = 32; o > 0; o >>= 1) s += __shfl_down(s, o, 64);
    __shared__ double wsum[4];
    int lane = tid & 63, w = tid >> 6;
    if (lane == 0) wsum[w] = s;
    __syncthreads();
    double tot = wsum[0] + wsum[1] + wsum[2] + wsum[3];
    float norm = fmaxf((float)sqrt(tot), 1e-12f);
    size_t base = (size_t)r * DD;
#pragma unroll
    for (int q = 0; q < 3; ++q) {
        int k = tid + q * 256;
        float v = (q == 0 ? v0 : (q == 1 ? v1 : v2)) / norm;
        x[base + k] = v;
        ushort h = f2bf(v);
        xh[base + k] = h;
        xl[base + k] = f2bf(v - bf2f(h));
    }
}

// ---------------------------------------------------------------------------
// k_colsum: g[k] = sum over rows of x[r][k], fp64.
// ---------------------------------------------------------------------------
__global__ __launch_bounds__(256) void k_colsum(const float* __restrict__ x,
                                                double* __restrict__ g) {
    int t = threadIdx.x;
    int r0 = blockIdx.x * 32;
    double s0 = 0.0, s1 = 0.0, s2 = 0.0;
    for (int r = r0; r < r0 + 32; ++r) {
        const float* xr = x + (size_t)r * DD;
        s0 += (double)xr[t];
        s1 += (double)xr[t + 256];
        s2 += (double)xr[t + 512];
    }
    atomicAdd(&g[t], s0);
    atomicAdd(&g[t + 256], s1);
    atomicAdd(&g[t + 512], s2);
}

// ---------------------------------------------------------------------------
// k_mean: mnum[r] = x_r.g - x_r.x_r (fp64); dd[r] = x_r.x_r (S diagonal).
// Exact mean path -- numerically deadly, do not approximate.
// ---------------------------------------------------------------------------
__global__ __launch_bounds__(256) void k_mean(const float* __restrict__ x,
                                              const double* __restrict__ g,
                                              double* __restrict__ mnum,
                                              double* __restrict__ dd) {
    int r = blockIdx.x * 4 + (threadIdx.x >> 6);
    int lane = threadIdx.x & 63;
    const float* xr = x + (size_t)r * DD;
    double xg = 0.0, xx = 0.0;
#pragma unroll
    for (int k = lane; k < DD; k += 64) {
        double xv = (double)xr[k];
        xg += xv * g[k];
        xx += xv * xv;
    }
#pragma unroll
    for (int o = 32; o > 0; o >>= 1) {
        xg += __shfl_down(xg, o, 64);
        xx += __shfl_down(xx, o, 64);
    }
    if (lane == 0) {
        mnum[r] = xg - xx;
        dd[r] = xx;
    }
}

// ---------------------------------------------------------------------------
// k_select: deterministic row-sorted compaction of "danger" rows
// (|mean_neg+eps| < 1e-5). Initializes dlist to -1 itself (single block).
// ---------------------------------------------------------------------------
__global__ __launch_bounds__(256) void k_select(const double* __restrict__ mnum,
                                                int* __restrict__ dlist) {
    __shared__ int cnts[256];
    int tid = threadIdx.x;
    dlist[tid] = -1;
    int r0 = tid * 32;
    int c = 0;
    for (int i = 0; i < 32; ++i) {
        double md = fabs(mnum[r0 + i] / 8191.0 + 1e-6);
        if (md < 1e-5) ++c;
    }
    cnts[tid] = c;
    __syncthreads();
    int pre = 0;
    for (int i = 0; i < tid; ++i) pre += cnts[i];
    for (int i = 0; i < 32; ++i) {
        int r = r0 + i;
        double md = fabs(mnum[r] / 8191.0 + 1e-6);
        if (md < 1e-5) {
            if (pre < NDMAX) dlist[pre] = r;
            ++pre;
        }
    }
}

// ---------------------------------------------------------------------------
// kloop12: the shared 256x256 x K=768 MFMA loop (12 K-tiles, 4 phases each,
// counted vmcnt(4), raw barriers, setprio). Constant A/B source pointers.
// LDS k-half arrays [256][32] bf16, slot swizzle li4^((l15>>1)&3); staging
// via global_load_lds w=16 with pre-swizzled per-lane source, linear dest.
// ---------------------------------------------------------------------------
__device__ __forceinline__ void kloop12(const ushort* __restrict__ XA,
                                        const ushort* __restrict__ XB,
                                        int gA0, int gA1, int gB0, int gB1,
                                        int aoff, int boff, int ld0, int ld1,
                                        ushort* LDS, f32x4 (&acc)[8][4]) {
    // prologue: stage tile 0, order Ak0,Bk0,Ak1,Bk1
    gload16(XA + gA0, LDS + ld0);              gload16(XA + gA1, LDS + ld1);
    gload16(XB + gB0, LDS + 16384 + ld0);      gload16(XB + gB1, LDS + 16384 + ld1);
    gload16(XA + gA0 + 32, LDS + 8192 + ld0);  gload16(XA + gA1 + 32, LDS + 8192 + ld1);
    gload16(XB + gB0 + 32, LDS + 24576 + ld0); gload16(XB + gB1 + 32, LDS + 24576 + ld1);
    asm volatile("s_waitcnt vmcnt(4)" ::: "memory");
    SCHED0(); BAR();

    for (int t = 0; t < 12; ++t) {
        const int cur = t & 1;
        ushort* Ak0 = LDS + cur * 32768;
        ushort* Ak1 = Ak0 + 8192;
        ushort* Bk0 = Ak0 + 16384;
        ushort* Bk1 = Ak0 + 24576;
        ushort* nA0 = LDS + (cur ^ 1) * 32768;
        ushort* nA1 = nA0 + 8192;
        ushort* nB0 = nA0 + 16384;
        ushort* nB1 = nA0 + 24576;
        const bool st = (t < 11);
        const int c1 = (t + 1) * 64;

        bf16x8 avA[4], avB[4], bv[4];
        // ---- P1: read A(f0-3,ks0)+B(ks0); stage Ak0(t+1); MFMA f0-3 ks0
#pragma unroll
        for (int f = 0; f < 4; ++f) avA[f] = *(const bf16x8*)(Ak0 + aoff + f * 512);
#pragma unroll
        for (int n = 0; n < 4; ++n) bv[n] = *(const bf16x8*)(Bk0 + boff + n * 512);
        if (st) { gload16(XA + gA0 + c1, nA0 + ld0); gload16(XA + gA1 + c1, nA0 + ld1); }
        SCHED0(); BAR(); SCHED0();
        __builtin_amdgcn_s_setprio(1);
#pragma unroll
        for (int f = 0; f < 4; ++f)
#pragma unroll
            for (int n = 0; n < 4; ++n)
                acc[f][n] = __builtin_amdgcn_mfma_f32_16x16x32_bf16(avA[f], bv[n], acc[f][n], 0, 0, 0);
        __builtin_amdgcn_s_setprio(0);
        SCHED0(); BAR();
        // ---- P2: read A(f4-7,ks0); stage Bk0(t+1); MFMA f4-7 ks0; vmcnt
#pragma unroll
        for (int f = 0; f < 4; ++f) avB[f] = *(const bf16x8*)(Ak0 + aoff + 2048 + f * 512);
        if (st) { gload16(XB + gB0 + c1, nB0 + ld0); gload16(XB + gB1 + c1, nB0 + ld1); }
        SCHED0(); BAR(); SCHED0();
        __builtin_amdgcn_s_setprio(1);
#pragma unroll
        for (int f = 0; f < 4; ++f)
#pragma unroll
            for (int n = 0; n < 4; ++n)
                acc[4 + f][n] = __builtin_amdgcn_mfma_f32_16x16x32_bf16(avB[f], bv[n], acc[4 + f][n], 0, 0, 0);
        __builtin_amdgcn_s_setprio(0);
        if (st) { asm volatile("s_waitcnt vmcnt(4)" ::: "memory"); }
        else    { asm volatile("s_waitcnt vmcnt(0)" ::: "memory"); }
        SCHED0(); BAR();
        // ---- P3: read A(f0-3,ks1)+B(ks1); stage Ak1(t+1); MFMA f0-3 ks1
#pragma unroll
        for (int f = 0; f < 4; ++f) avA[f] = *(const bf16x8*)(Ak1 + aoff + f * 512);
#pragma unroll
        for (int n = 0; n < 4; ++n) bv[n] = *(const bf16x8*)(Bk1 + boff + n * 512);
        if (st) { gload16(XA + gA0 + c1 + 32, nA1 + ld0); gload16(XA + gA1 + c1 + 32, nA1 + ld1); }
        SCHED0(); BAR(); SCHED0();
        __builtin_amdgcn_s_setprio(1);
#pragma unroll
        for (int f = 0; f < 4; ++f)
#pragma unroll
            for (int n = 0; n < 4; ++n)
                acc[f][n] = __builtin_amdgcn_mfma_f32_16x16x32_bf16(avA[f], bv[n], acc[f][n], 0, 0, 0);
        __builtin_amdgcn_s_setprio(0);
        SCHED0(); BAR();
        // ---- P4: read A(f4-7,ks1); stage Bk1(t+1); MFMA f4-7 ks1; vmcnt
#pragma unroll
        for (int f = 0; f < 4; ++f) avB[f] = *(const bf16x8*)(Ak1 + aoff + 2048 + f * 512);
        if (st) { gload16(XB + gB0 + c1 + 32, nB1 + ld0); gload16(XB + gB1 + c1 + 32, nB1 + ld1); }
        SCHED0(); BAR(); SCHED0();
        __builtin_amdgcn_s_setprio(1);
#pragma unroll
        for (int f = 0; f < 4; ++f)
#pragma unroll
            for (int n = 0; n < 4; ++n)
                acc[4 + f][n] = __builtin_amdgcn_mfma_f32_16x16x32_bf16(avB[f], bv[n], acc[4 + f][n], 0, 0, 0);
        __builtin_amdgcn_s_setprio(0);
        if (st) { asm volatile("s_waitcnt vmcnt(4)" ::: "memory"); }
        SCHED0(); BAR();
    }
}

// ---------------------------------------------------------------------------
// k_cube: bf16 MFMA pass, all blocks ~uniform length.
//  - bids 0..95: strip-partial blocks (seg = bid/32 in {hh, lo.hi, hi.lo},
//    colchunk = bid%32): danger rows (gathered) x 256 cols, 12 K-tiles;
//    STORE partial S (f32) into Sb[seg] -- no cube, no atomics.
//  - bids 96..607: big 256^2 triangle tiles, 12 K-tiles (hh only),
//    XCD-bijective swizzle; cube + row/col sums via symmetry.
//  - bids 608..671: quarter tiles (128^2) of the last 16 triangle tiles.
// ---------------------------------------------------------------------------
__global__ __launch_bounds__(512, 2) void k_cube(const ushort* __restrict__ xh,
                                                 const ushort* __restrict__ xl,
                                                 const int* __restrict__ dlist,
                                                 float* __restrict__ Sb,
                                                 float* __restrict__ rc) {
    __shared__ ushort LDS[65536];  // 128 KiB

    const int bid = blockIdx.x;
    const int tid = threadIdx.x;
    const int lane = tid & 63;
    const int wid = tid >> 6;
    const int l15 = lane & 15, li4 = lane >> 4;
    const int swzrd = ((li4 ^ ((l15 >> 1) & 3)) << 3);

    if (bid >= 608) {
        // ---- quarter tile: 128x128, K=768 (hh only) ----
        const int qid = bid - 608;
        int wg = 512 + (qid >> 2), q = qid & 3;
        int bi = 0, rem = wg;
        while (rem >= 32 - bi) { rem -= 32 - bi; ++bi; }
        const int bj = bi + rem;
        const int gr = bi * 2 + (q >> 1), gc = bj * 2 + (q & 1);
        if (gc < gr) return;
        const int R0 = gr * 128, C0 = gc * 128;
        const int wm = wid >> 2, wn = wid & 3;  // per-wave 64x32
        const int aoff = (wm * 64 + l15) * 32 + swzrd;
        const int boff = (wn * 32 + l15) * 32 + swzrd;
        const int sl = ((tid & 3) ^ ((tid >> 3) & 3)) * 8;
        const int gA0 = (R0 + (tid >> 2)) * DD + sl;
        const int gB0 = (C0 + (tid >> 2)) * DD + sl;
        const int ld0 = tid * 8;

        f32x4 acc[4][2];
#pragma unroll
        for (int f = 0; f < 4; ++f)
#pragma unroll
            for (int n = 0; n < 2; ++n) acc[f][n] = (f32x4){0.f, 0.f, 0.f, 0.f};

        gload16(xh + gA0, LDS + ld0);
        gload16(xh + gB0, LDS + 8192 + ld0);
        gload16(xh + gA0 + 32, LDS + 4096 + ld0);
        gload16(xh + gB0 + 32, LDS + 12288 + ld0);
        asm volatile("s_waitcnt vmcnt(0)" ::: "memory");
        SCHED0(); BAR();

        for (int t = 0; t < 12; ++t) {
            const int cur = t & 1;
            ushort* A0 = LDS + cur * 16384;
            ushort* A1 = A0 + 4096;
            ushort* B0 = A0 + 8192;
            ushort* B1 = A0 + 12288;
            ushort* nA0 = LDS + (cur ^ 1) * 16384;
            const bool st = (t < 11);
            const int c1 = (t + 1) * 64;

            bf16x8 av0[4], av1[4], bv0[2], bv1[2];
#pragma unroll
            for (int f = 0; f < 4; ++f) {
                av0[f] = *(const bf16x8*)(A0 + aoff + f * 512);
                av1[f] = *(const bf16x8*)(A1 + aoff + f * 512);
            }
#pragma unroll
            for (int n = 0; n < 2; ++n) {
                bv0[n] = *(const bf16x8*)(B0 + boff + n * 512);
                bv1[n] = *(const bf16x8*)(B1 + boff + n * 512);
            }
            if (st) {
                gload16(xh + gA0 + c1, nA0 + ld0);
                gload16(xh + gB0 + c1, nA0 + 8192 + ld0);
                gload16(xh + gA0 + c1 + 32, nA0 + 4096 + ld0);
                gload16(xh + gB0 + c1 + 32, nA0 + 12288 + ld0);
            }
            __builtin_amdgcn_s_setprio(1);
#pragma unroll
            for (int f = 0; f < 4; ++f)
#pragma unroll
                for (int n = 0; n < 2; ++n)
                    acc[f][n] = __builtin_amdgcn_mfma_f32_16x16x32_bf16(av0[f], bv0[n], acc[f][n], 0, 0, 0);
#pragma unroll
            for (int f = 0; f < 4; ++f)
#pragma unroll
                for (int n = 0; n < 2; ++n)
                    acc[f][n] = __builtin_amdgcn_mfma_f32_16x16x32_bf16(av1[f], bv1[n], acc[f][n], 0, 0, 0);
            __builtin_amdgcn_s_setprio(0);
            asm volatile("s_waitcnt vmcnt(0)" ::: "memory");
            SCHED0(); BAR();
        }

        const bool dblk = (gr == gc);
        float rsum[4][4], csum[2];
#pragma unroll
        for (int n = 0; n < 2; ++n) csum[n] = 0.f;
#pragma unroll
        for (int f = 0; f < 4; ++f)
#pragma unroll
            for (int r = 0; r < 4; ++r) rsum[f][r] = 0.f;
#pragma unroll
        for (int f = 0; f < 4; ++f)
#pragma unroll
            for (int n = 0; n < 2; ++n)
#pragma unroll
                for (int r = 0; r < 4; ++r) {
                    float s = acc[f][n][r];
                    float c = s * s * s;
                    int ri = wm * 64 + f * 16 + li4 * 4 + r;
                    int cj = wn * 32 + n * 16 + l15;
                    if (dblk && ri == cj) c = 0.f;
                    rsum[f][r] += c;
                    csum[n] += c;
                }
#pragma unroll
        for (int o = 1; o < 16; o <<= 1)
#pragma unroll
            for (int f = 0; f < 4; ++f)
#pragma unroll
                for (int r = 0; r < 4; ++r)
                    rsum[f][r] += __shfl_xor(rsum[f][r], o, 64);
        if (l15 == 0) {
#pragma unroll
            for (int f = 0; f < 4; ++f)
#pragma unroll
                for (int r = 0; r < 4; ++r)
                    atomicAdd(&rc[R0 + wm * 64 + f * 16 + li4 * 4 + r], rsum[f][r]);
        }
        if (!dblk) {
#pragma unroll
            for (int o = 16; o < 64; o <<= 1)
#pragma unroll
                for (int n = 0; n < 2; ++n) csum[n] += __shfl_xor(csum[n], o, 64);
            if (li4 == 0) {
#pragma unroll
                for (int n = 0; n < 2; ++n)
                    atomicAdd(&rc[C0 + wn * 32 + n * 16 + l15], csum[n]);
            }
        }
        return;
    }

    // ---- shared 256x256 path: strip-partial (bid<96) or big tile ----
    const bool strip = (bid < 96);
    int bi = 0, bj = 0, seg = 0, cc = 0;
    if (strip) {
        seg = bid >> 5;
        cc = bid & 31;
    } else {
        const int idx = bid - 96;
        int wg = (idx & 7) * 64 + (idx >> 3);
        int rem = wg;
        while (rem >= 32 - bi) { rem -= 32 - bi; ++bi; }
        bj = bi + rem;
    }
    const int wm = wid >> 2, wn = wid & 3;  // 2M x 4N, per-wave 128x64
    const int aoff = (wm * 128 + l15) * 32 + swzrd;
    const int boff = (wn * 64 + l15) * 32 + swzrd;
    const int li0 = tid, li1 = tid + 512;
    const int sl0 = ((li0 & 3) ^ ((li0 >> 3) & 3)) * 8;
    const int sl1 = ((li1 & 3) ^ ((li1 >> 3) & 3)) * 8;
    int ar0, ar1, bt;
    const ushort *XA, *XB;
    if (strip) {
        ar0 = dlist[li0 >> 2]; if (ar0 < 0) ar0 = 0;
        ar1 = dlist[li1 >> 2]; if (ar1 < 0) ar1 = 0;
        bt = cc;
        XA = (seg == 1) ? xl : xh;
        XB = (seg == 2) ? xl : xh;
    } else {
        ar0 = bi * 256 + (li0 >> 2);
        ar1 = bi * 256 + (li1 >> 2);
        bt = bj;
        XA = xh; XB = xh;
    }
    const int gA0 = ar0 * DD + sl0;
    const int gA1 = ar1 * DD + sl1;
    const int gB0 = (bt * 256 + (li0 >> 2)) * DD + sl0;
    const int gB1 = (bt * 256 + (li1 >> 2)) * DD + sl1;
    const int ld0 = li0 * 8, ld1 = li1 * 8;

    f32x4 acc[8][4];
#pragma unroll
    for (int f = 0; f < 8; ++f)
#pragma unroll
        for (int n = 0; n < 4; ++n) acc[f][n] = (f32x4){0.f, 0.f, 0.f, 0.f};

    kloop12(XA, XB, gA0, gA1, gB0, gB1, aoff, boff, ld0, ld1, LDS, acc);

    if (strip) {
        // store partial S by danger slot (f32); finish pass cubes later
#pragma unroll
        for (int f = 0; f < 8; ++f)
#pragma unroll
            for (int n = 0; n < 4; ++n)
#pragma unroll
                for (int r = 0; r < 4; ++r) {
                    size_t slot = (size_t)(seg * 256 + wm * 128 + f * 16 + li4 * 4 + r);
                    Sb[(slot << 13) + cc * 256 + wn * 64 + n * 16 + l15] = acc[f][n][r];
                }
        return;
    }

    // big-tile epilogue: cube, skip diag, row + col (symmetry) sums
    const bool dblk = (bi == bj);
    float rsum[8][4], csum[4];
#pragma unroll
    for (int n = 0; n < 4; ++n) csum[n] = 0.f;
#pragma unroll
    for (int f = 0; f < 8; ++f)
#pragma unroll
        for (int r = 0; r < 4; ++r) rsum[f][r] = 0.f;
#pragma unroll
    for (int f = 0; f < 8; ++f)
#pragma unroll
        for (int n = 0; n < 4; ++n)
#pragma unroll
            for (int r = 0; r < 4; ++r) {
                float s = acc[f][n][r];
                float c = s * s * s;
                int ri = wm * 128 + f * 16 + li4 * 4 + r;
                int cj = wn * 64 + n * 16 + l15;
                if (dblk && ri == cj) c = 0.f;
                rsum[f][r] += c;
                csum[n] += c;
            }
#pragma unroll
    for (int o = 1; o < 16; o <<= 1)
#pragma unroll
        for (int f = 0; f < 8; ++f)
#pragma unroll
            for (int r = 0; r < 4; ++r)
                rsum[f][r] += __shfl_xor(rsum[f][r], o, 64);
    if (l15 == 0) {
#pragma unroll
        for (int f = 0; f < 8; ++f)
#pragma unroll
            for (int r = 0; r < 4; ++r)
                atomicAdd(&rc[bi * 256 + wm * 128 + f * 16 + li4 * 4 + r], rsum[f][r]);
    }
    if (!dblk) {
#pragma unroll
        for (int o = 16; o < 64; o <<= 1)
#pragma unroll
            for (int n = 0; n < 4; ++n) csum[n] += __shfl_xor(csum[n], o, 64);
        if (li4 == 0) {
#pragma unroll
            for (int n = 0; n < 4; ++n)
                atomicAdd(&rc[bj * 256 + wn * 64 + n * 16 + l15], csum[n]);
        }
    }
}

// ---------------------------------------------------------------------------
// k_cubefin: per danger slot, correction = sum_c [(s0+s1+s2)^3 - s0^3]
// (skip c == drow; s0 is bitwise-equal to the big pass's hh value, so the
// subtraction exactly removes the hh-cube already in rc).
// ---------------------------------------------------------------------------
__global__ __launch_bounds__(256) void k_cubefin(const float* __restrict__ Sb,
                                                 const int* __restrict__ dlist,
                                                 float* __restrict__ rc) {
    const int slot = blockIdx.x;
    const int drow = dlist[slot];
    if (drow < 0) return;
    const int tid = threadIdx.x;
    const float* s0p = Sb + ((size_t)slot << 13);
    const float* s1p = Sb + ((size_t)(256 + slot) << 13);
    const float* s2p = Sb + ((size_t)(512 + slot) << 13);
    float sum = 0.f;
    for (int c = tid; c < VV; c += 256) {
        float s0 = s0p[c];
        float sf = s0 + s1p[c] + s2p[c];
        float d = sf * sf * sf - s0 * s0 * s0;
        if (c == drow) d = 0.f;
        sum += d;
    }
    __shared__ float red[256];
    red[tid] = sum;
    __syncthreads();
    for (int o = 128; o > 0; o >>= 1) {
        if (tid < o) red[tid] += red[tid + o];
        __syncthreads();
    }
    if (tid == 0) atomicAdd(&rc[drow], red[0]);
}

// ---------------------------------------------------------------------------
// k_final: out = collapse + 0.2 * sum_i rc_i / (mnum_i/8191 + 1e-6)
// ---------------------------------------------------------------------------
__global__ __launch_bounds__(256) void k_final(const float* __restrict__ rc,
                                               const double* __restrict__ mnum,
                                               const double* __restrict__ dd,
                                               float* __restrict__ out) {
    int tid = threadIdx.x;
    double acc = 0.0, col = 0.0;
    for (int r = tid; r < VV; r += 256) {
        double m = mnum[r] / 8191.0 + 1e-6;
        acc += (double)rc[r] / m;
        double dm = dd[r] - 1.0;
        col += dm * dm;
    }
    __shared__ double sa[256], sc[256];
    sa[tid] = acc;
    sc[tid] = col;
    __syncthreads();
    for (int o = 128; o > 0; o >>= 1) {
        if (tid < o) {
            sa[tid] += sa[tid + o];
            sc[tid] += sc[tid + o];
        }
        __syncthreads();
    }
    if (tid == 0) out[0] = (float)(sc[0] + 0.2 * sa[0]);
}

// ---------------------------------------------------------------------------
extern "C" void kernel_launch(void* const* d_in, const int* in_sizes, int n_in,
                              void* d_out, int out_size, void* d_ws, size_t ws_size,
                              hipStream_t stream) {
    const float* t = (const float*)d_in[0];
    float* out = (float*)d_out;

    char* ws = (char*)d_ws;
    float* x = (float*)ws;                                   // 25.2 MB
    float* Sb = (float*)ws;  // reuses x after k_mean: 3*256*8192*4B = 24 MB
    size_t off = (size_t)VV * DD * sizeof(float);
    ushort* xh = (ushort*)(ws + off); off += (size_t)VV * DD * sizeof(ushort);
    ushort* xl = (ushort*)(ws + off); off += (size_t)VV * DD * sizeof(ushort);
    double* g = (double*)(ws + off);  off += DD * sizeof(double);
    double* mnum = (double*)(ws + off); off += VV * sizeof(double);
    double* dd = (double*)(ws + off);  off += VV * sizeof(double);
    float* rc = (float*)(ws + off);    off += VV * sizeof(float);
    int* dlist = (int*)(ws + off);     off += NDMAX * sizeof(int);

    hipMemsetAsync(g, 0, DD * sizeof(double), stream);
    hipMemsetAsync(rc, 0, VV * sizeof(float), stream);

    k_normpack<<<VV, 256, 0, stream>>>(t, x, xh, xl);
    k_colsum<<<256, 256, 0, stream>>>(x, g);
    k_mean<<<VV / 4, 256, 0, stream>>>(x, g, mnum, dd);
    k_select<<<1, 256, 0, stream>>>(mnum, dlist);
    k_cube<<<672, 512, 0, stream>>>(xh, xl, dlist, Sb, rc);
    k_cubefin<<<NDMAX, 256, 0, stream>>>(Sb, dlist, rc);
    k_final<<<1, 256, 0, stream>>>(rc, mnum, dd, out);
}